// Round 4
// baseline (721.431 us; speedup 1.0000x reference)
//
#include <hip/hip_runtime.h>

typedef unsigned short u16;
typedef __bf16 bf16x8 __attribute__((ext_vector_type(8)));
typedef float f32x4 __attribute__((ext_vector_type(4)));

constexpr int NB = 128;   // batch
constexpr int CC = 256;   // channels
constexpr int TT = 32;
constexpr int VV = 25;
constexpr int SSS = 3;
constexpr int PIX = 800;  // T*V
constexpr float EPSV = 1e-5f;

// ---------------- workspace layout (bytes) ----------------
// total required: 266,338,304 bytes (~254 MiB)
constexpr size_t OFF_PE  = 0;                        // 6400 f32
constexpr size_t OFF_W1  = 64*1024;                  // 384x256 bf16
constexpr size_t OFF_WK2 = OFF_W1  + 256*1024;       // 256x1024 bf16
constexpr size_t OFF_WFF = OFF_WK2 + 512*1024;       // 256x256 bf16
constexpr size_t OFF_WD2 = OFF_WFF + 128*1024;       // 256x256 bf16
constexpr size_t OFF_B1  = OFF_WD2 + 128*1024;       // 384 f32
constexpr size_t OFF_BK2 = OFF_B1  + 4096;           // 256 f32
constexpr size_t OFF_BFF = OFF_BK2 + 4096;
constexpr size_t OFF_BD2 = OFF_BFF + 4096;
constexpr size_t OFF_ATT = 2ull*1024*1024;           // 128*3*625 f32
constexpr size_t OFF_XB  = 4ull*1024*1024;           // xb [128][800][256] bf16 = 52,428,800
constexpr size_t OFF_BIG = OFF_XB + 52428800ull;     // region: qkb [128][1024][384] (100.7MB), later Pb [128][800][768] (157.3MB), later y4b (52.4MB)
constexpr size_t OFF_Y3  = OFF_BIG + 157286400ull;   // region: yb then y3b [128][800][256] bf16

__device__ __forceinline__ float bf2f(u16 h) {
  union { unsigned u; float f; } c; c.u = ((unsigned)h) << 16; return c.f;
}
__device__ __forceinline__ u16 f2bf(float f) {
  union { float f; unsigned u; } c; c.f = f;
  unsigned r = c.u + 0x7fffu + ((c.u >> 16) & 1u);
  return (u16)(r >> 16);
}
__device__ __forceinline__ float lrelu(float z) { return z >= 0.f ? z : 0.1f*z; }

// ---------------- prep: fold BN into bf16 weights, PE table, pad-zero qkb ----------------
__global__ void prep_k(
    const float* __restrict__ in_w,  const float* __restrict__ in_b,
    const float* __restrict__ out_w, const float* __restrict__ out_b,
    const float* __restrict__ d1_w,  const float* __restrict__ d1_b,
    const float* __restrict__ d2_w,  const float* __restrict__ d2_b,
    const float* __restrict__ ff_w,  const float* __restrict__ ff_b,
    const float* __restrict__ out_g, const float* __restrict__ out_be, const float* __restrict__ out_m, const float* __restrict__ out_v,
    const float* __restrict__ d1_g,  const float* __restrict__ d1_be,  const float* __restrict__ d1_m,  const float* __restrict__ d1_v,
    const float* __restrict__ d2_g,  const float* __restrict__ d2_be,  const float* __restrict__ d2_m,  const float* __restrict__ d2_v,
    const float* __restrict__ ff_g,  const float* __restrict__ ff_be,  const float* __restrict__ ff_m,  const float* __restrict__ ff_v,
    float* __restrict__ pe, u16* __restrict__ w1b, float* __restrict__ b1,
    u16* __restrict__ wk2, float* __restrict__ bk2,
    u16* __restrict__ wff, float* __restrict__ bff,
    u16* __restrict__ wd2, float* __restrict__ bd2,
    u16* __restrict__ qkb)
{
  const int id  = blockIdx.x*blockDim.x + threadIdx.x;
  const int nth = gridDim.x*blockDim.x;
  // PE table: pe[ch][v]; ch=2j -> sin(v*div[j]), ch=2j+1 -> cos
  for (int i = id; i < CC*VV; i += nth) {
    int ch = i / VV, vv = i - ch*VV;
    int j = ch >> 1;
    float ang = (float)vv * expf((float)j * (-2.0f*logf(10000.0f)/(float)CC));
    pe[i] = (ch & 1) ? cosf(ang) : sinf(ang);
  }
  for (int i = id; i < 384*CC; i += nth) w1b[i] = f2bf(in_w[i]);
  for (int i = id; i < 384;    i += nth) b1[i] = in_b[i];
  // fused out-conv (k<768) + d1-conv (k>=768), both with BN folded
  for (int i = id; i < CC*1024; i += nth) {
    int o = i >> 10, k = i & 1023;
    float w;
    if (k < 768) { float inv = out_g[o]*rsqrtf(out_v[o]+EPSV); w = out_w[o*768+k]*inv; }
    else         { float inv = d1_g[o]*rsqrtf(d1_v[o]+EPSV);   w = d1_w[o*256+(k-768)]*inv; }
    wk2[i] = f2bf(w);
  }
  for (int i = id; i < CC*CC; i += nth) {
    int o = i >> 8;
    wff[i] = f2bf(ff_w[i]*(ff_g[o]*rsqrtf(ff_v[o]+EPSV)));
    wd2[i] = f2bf(d2_w[i]*(d2_g[o]*rsqrtf(d2_v[o]+EPSV)));
  }
  for (int i = id; i < CC; i += nth) {
    float invo = out_g[i]*rsqrtf(out_v[i]+EPSV);
    float invd = d1_g[i]*rsqrtf(d1_v[i]+EPSV);
    bk2[i] = out_b[i]*invo + out_be[i] - out_m[i]*invo
           + d1_b[i]*invd  + d1_be[i]  - d1_m[i]*invd;
    float invf = ff_g[i]*rsqrtf(ff_v[i]+EPSV);
    bff[i] = ff_b[i]*invf + ff_be[i] - ff_m[i]*invf;
    float inv2 = d2_g[i]*rsqrtf(d2_v[i]+EPSV);
    bd2[i] = d2_b[i]*inv2 + d2_be[i] - d2_m[i]*inv2;
  }
  // zero the pad rows (v=25..31) of qkb [n][t*32+v][384]
  for (int i = id; i < NB*TT*7*384; i += nth) {
    int ch = i % 384; int r = i / 384;
    int pr = r % 7; int t = (r/7) % TT; int n = r / (7*TT);
    qkb[((size_t)n*1024 + (size_t)t*32 + 25 + pr)*384 + ch] = 0;
  }
}

// ---------------- k0: yb[n][p][c] = bf16(x + pe) (pixel-major transpose) ----------------
__global__ __launch_bounds__(256) void k0_pe_cvt(
    const float* __restrict__ x, const float* __restrict__ pe, u16* __restrict__ yb)
{
  __shared__ float xt[CC*VV];
  __shared__ float pl[CC*VV];
  const int t = blockIdx.x, n = blockIdx.y;
  const float* xs = x + (size_t)n*CC*PIX + t*VV;
  for (int f = threadIdx.x; f < CC*VV; f += 256) {
    int c = f / VV, u = f - c*VV;
    xt[f] = xs[(size_t)c*PIX + u];
    pl[f] = pe[f];
  }
  __syncthreads();
  const int c = threadIdx.x;
  u16* yrow = yb + ((size_t)n*PIX + t*VV)*CC + c;
  #pragma unroll
  for (int u = 0; u < VV; ++u)
    yrow[(size_t)u*CC] = f2bf(xt[c*VV+u] + pl[c*VV+u]);
}

// ---------------- p_k: Pb[n][p][s*256+c] = sum_u x*att ; xb[n][p][c] = bf16(x) ----------------
__global__ __launch_bounds__(256) void p_k(
    const float* __restrict__ x, const float* __restrict__ attw,
    u16* __restrict__ Pb, u16* __restrict__ xb)
{
  __shared__ float xt[CC*VV];
  __shared__ float al[SSS*VV*VV];
  const int t = blockIdx.x, n = blockIdx.y;
  const float* xs = x + (size_t)n*CC*PIX + t*VV;
  for (int f = threadIdx.x; f < CC*VV; f += 256) {
    int c = f / VV, u = f - c*VV;
    xt[f] = xs[(size_t)c*PIX + u];
  }
  for (int f = threadIdx.x; f < SSS*VV*VV; f += 256)
    al[f] = attw[(size_t)n*SSS*VV*VV + f];
  __syncthreads();
  const int c = threadIdx.x;
  float xr[VV];
  #pragma unroll
  for (int u = 0; u < VV; ++u) xr[u] = xt[c*VV+u];
  u16* xrow = xb + ((size_t)n*PIX + t*VV)*CC + c;
  #pragma unroll
  for (int u = 0; u < VV; ++u) xrow[(size_t)u*CC] = f2bf(xr[u]);
  for (int s = 0; s < SSS; ++s) {
    u16* prow = Pb + ((size_t)n*PIX + t*VV)*768 + s*CC + c;
    for (int v = 0; v < VV; ++v) {
      float a = 0.f;
      #pragma unroll
      for (int u = 0; u < VV; ++u) a += xr[u]*al[(s*VV+u)*VV+v];
      prow[(size_t)v*768] = f2bf(a);
    }
  }
}

// ---------------- att: per (n,s) 1-wave MFMA Q^T K over (ic,t), tanh epilogue ----------------
__global__ __launch_bounds__(64) void att_k(
    const u16* __restrict__ qkb, const float* __restrict__ alphas,
    const float* __restrict__ att0, float* __restrict__ attw)
{
  const int s = blockIdx.x, n = blockIdx.y, lane = threadIdx.x;
  const u16* qb = qkb + (size_t)n*1024*384 + s*64;
  const u16* kb = qb + 192;   // k channels start at 3*64
  f32x4 acc[2][2];
  #pragma unroll
  for (int i = 0; i < 2; ++i)
    #pragma unroll
    for (int j = 0; j < 2; ++j) acc[i][j] = f32x4{0.f,0.f,0.f,0.f};

  for (int t = 0; t < TT; ++t) {
    const u16* qrow = qb + (size_t)t*32*384;
    const u16* krow = kb + (size_t)t*32*384;
    #pragma unroll
    for (int ks = 0; ks < 2; ++ks) {
      const int ko = ks*32 + (lane>>4)*8;
      bf16x8 a0 = *(const bf16x8*)(qrow + (size_t)(lane&15)*384 + ko);
      bf16x8 a1 = *(const bf16x8*)(qrow + (size_t)(16+(lane&15))*384 + ko);
      bf16x8 b0 = *(const bf16x8*)(krow + (size_t)(lane&15)*384 + ko);
      bf16x8 b1 = *(const bf16x8*)(krow + (size_t)(16+(lane&15))*384 + ko);
      acc[0][0] = __builtin_amdgcn_mfma_f32_16x16x32_bf16(a0, b0, acc[0][0], 0,0,0);
      acc[0][1] = __builtin_amdgcn_mfma_f32_16x16x32_bf16(a0, b1, acc[0][1], 0,0,0);
      acc[1][0] = __builtin_amdgcn_mfma_f32_16x16x32_bf16(a1, b0, acc[1][0], 0,0,0);
      acc[1][1] = __builtin_amdgcn_mfma_f32_16x16x32_bf16(a1, b1, acc[1][1], 0,0,0);
    }
  }
  const float alpha = alphas[s];
  const float sc = 1.0f/2048.0f;
  #pragma unroll
  for (int fm = 0; fm < 2; ++fm)
    #pragma unroll
    for (int fn = 0; fn < 2; ++fn)
      #pragma unroll
      for (int j = 0; j < 4; ++j) {
        int u = fm*16 + (lane>>4)*4 + j;
        int v = fn*16 + (lane&15);
        if (u < VV && v < VV)
          attw[(size_t)n*SSS*VV*VV + s*VV*VV + u*VV + v] =
              tanhf(acc[fm][fn][j]*sc)*alpha + att0[s*VV*VV + u*VV + v];
      }
}

// ---------------- GEMM: OUT[o, p] = W[o,:] . Bpm[p,:] + bias, per-n ----------------
// m97-style: 2-barrier dbuf, global_load_lds width 16. Block tile 128x160, 8 waves (4Mx2N),
// wave tile 32x80, 16x16x32 bf16 MFMA.
// EPI: 0 = store bf16 to qkb [n][ (p/25)*32+p%25 ][384] (padded-row layout)
//      1 = lrelu, store bf16 pixel-major [n][p][256]
//      2 = lrelu, store bf16 chan-major [n][256][800]
//      3 = +y4b, lrelu, store f32 chan-major [n][256][800]
template<int KTOT, int NKC0, int BS0, int BS1, int EPI>
__global__ __launch_bounds__(512, 1)
void gemm_k(const u16* __restrict__ W, const float* __restrict__ bias,
            const u16* __restrict__ B0, const u16* __restrict__ B1,
            void* __restrict__ outv, const u16* __restrict__ y4b)
{
  constexpr int NKC = KTOT/64;
  __shared__ u16 As[2][128*64];
  __shared__ u16 Bs[2][160*64];
  const int tid = threadIdx.x;
  const int lane = tid & 63, wid = tid >> 6;
  const int wm = wid >> 1, wn = wid & 1;
  const int pt = blockIdx.x, mt = blockIdx.y, n = blockIdx.z;
  const int m0 = mt*128, p0 = pt*160;
  const int lr = lane >> 3;        // 0..7
  const int lc = (lane & 7) * 8;   // element offset within 64-wide k chunk

  f32x4 acc[2][5];
  #pragma unroll
  for (int i = 0; i < 2; ++i)
    #pragma unroll
    for (int j = 0; j < 5; ++j) acc[i][j] = f32x4{0.f,0.f,0.f,0.f};

  auto stage = [&](int buf, int kc) {
    const u16* wsrc = W + (size_t)m0*KTOT + (size_t)kc*64;
    for (int g = wid; g < 16; g += 8) {
      const u16* src = wsrc + (size_t)(g*8 + lr)*KTOT + lc;
      __builtin_amdgcn_global_load_lds(
          (const __attribute__((address_space(1))) void*)src,
          (__attribute__((address_space(3))) void*)(&As[buf][g*512]), 16, 0, 0);
    }
    const u16* bbase; int bs;
    if (NKC0 >= NKC || kc < NKC0) {
      bbase = B0 + ((size_t)n*PIX + p0)*BS0 + (size_t)kc*64; bs = BS0;
    } else {
      bbase = B1 + ((size_t)n*PIX + p0)*BS1 + (size_t)(kc-NKC0)*64; bs = BS1;
    }
    for (int g = wid; g < 20; g += 8) {
      const u16* src = bbase + (size_t)(g*8 + lr)*bs + lc;
      __builtin_amdgcn_global_load_lds(
          (const __attribute__((address_space(1))) void*)src,
          (__attribute__((address_space(3))) void*)(&Bs[buf][g*512]), 16, 0, 0);
    }
  };

  auto compute = [&](int buf) {
    #pragma unroll
    for (int ks = 0; ks < 2; ++ks) {
      const int ko = ks*32 + (lane>>4)*8;
      bf16x8 a0 = *(const bf16x8*)&As[buf][(wm*32 + (lane&15))*64 + ko];
      bf16x8 a1 = *(const bf16x8*)&As[buf][(wm*32 + 16 + (lane&15))*64 + ko];
      bf16x8 bfr[5];
      #pragma unroll
      for (int fn = 0; fn < 5; ++fn)
        bfr[fn] = *(const bf16x8*)&Bs[buf][(wn*80 + fn*16 + (lane&15))*64 + ko];
      #pragma unroll
      for (int fn = 0; fn < 5; ++fn) {
        acc[0][fn] = __builtin_amdgcn_mfma_f32_16x16x32_bf16(a0, bfr[fn], acc[0][fn], 0,0,0);
        acc[1][fn] = __builtin_amdgcn_mfma_f32_16x16x32_bf16(a1, bfr[fn], acc[1][fn], 0,0,0);
      }
    }
  };

  stage(0, 0);
  __syncthreads();
  for (int kc = 0; kc < NKC; ++kc) {
    if (kc + 1 < NKC) stage((kc+1)&1, kc+1);
    compute(kc&1);
    __syncthreads();
  }

  // epilogue
  const int oc = (lane>>4)*4, pc = lane&15;
  #pragma unroll
  for (int fm = 0; fm < 2; ++fm) {
    const int o = m0 + wm*32 + fm*16 + oc;
    const float4 bv = *(const float4*)&bias[o];
    #pragma unroll
    for (int fn = 0; fn < 5; ++fn) {
      const int p = p0 + wn*80 + fn*16 + pc;
      f32x4 v = acc[fm][fn];
      float r0 = v[0]+bv.x, r1 = v[1]+bv.y, r2 = v[2]+bv.z, r3 = v[3]+bv.w;
      if constexpr (EPI == 0) {
        int row = (p/VV)*32 + (p%VV);
        ushort4 st; st.x=f2bf(r0); st.y=f2bf(r1); st.z=f2bf(r2); st.w=f2bf(r3);
        *(ushort4*)((u16*)outv + ((size_t)n*1024 + row)*384 + o) = st;
      } else if constexpr (EPI == 1) {
        ushort4 st;
        st.x=f2bf(lrelu(r0)); st.y=f2bf(lrelu(r1)); st.z=f2bf(lrelu(r2)); st.w=f2bf(lrelu(r3));
        *(ushort4*)((u16*)outv + ((size_t)n*PIX + p)*256 + o) = st;
      } else if constexpr (EPI == 2) {
        u16* op = (u16*)outv + ((size_t)n*256 + o)*PIX + p;
        op[0]      = f2bf(lrelu(r0));
        op[PIX]    = f2bf(lrelu(r1));
        op[2*PIX]  = f2bf(lrelu(r2));
        op[3*PIX]  = f2bf(lrelu(r3));
      } else {
        const u16* yp = y4b + ((size_t)n*256 + o)*PIX + p;
        float* op = (float*)outv + ((size_t)n*256 + o)*PIX + p;
        op[0]      = lrelu(r0 + bf2f(yp[0]));
        op[PIX]    = lrelu(r1 + bf2f(yp[PIX]));
        op[2*PIX]  = lrelu(r2 + bf2f(yp[2*PIX]));
        op[3*PIX]  = lrelu(r3 + bf2f(yp[3*PIX]));
      }
    }
  }
}

extern "C" void kernel_launch(void* const* d_in, const int* in_sizes, int n_in,
                              void* d_out, int out_size, void* d_ws, size_t ws_size,
                              hipStream_t stream)
{
  const float* x      = (const float*)d_in[0];
  const float* in_w   = (const float*)d_in[1];
  const float* in_b   = (const float*)d_in[2];
  const float* alphas = (const float*)d_in[3];
  const float* att0   = (const float*)d_in[4];
  const float* out_w  = (const float*)d_in[5];
  const float* out_b  = (const float*)d_in[6];
  const float* d1_w   = (const float*)d_in[7];
  const float* d1_b   = (const float*)d_in[8];
  const float* d2_w   = (const float*)d_in[9];
  const float* d2_b   = (const float*)d_in[10];
  const float* ff_w   = (const float*)d_in[11];
  const float* ff_b   = (const float*)d_in[12];
  const float* out_g  = (const float*)d_in[13];
  const float* out_be = (const float*)d_in[14];
  const float* out_m  = (const float*)d_in[15];
  const float* out_v  = (const float*)d_in[16];
  const float* d1_g   = (const float*)d_in[17];
  const float* d1_be  = (const float*)d_in[18];
  const float* d1_m   = (const float*)d_in[19];
  const float* d1_v   = (const float*)d_in[20];
  const float* d2_g   = (const float*)d_in[21];
  const float* d2_be  = (const float*)d_in[22];
  const float* d2_m   = (const float*)d_in[23];
  const float* d2_v   = (const float*)d_in[24];
  const float* ff_g   = (const float*)d_in[25];
  const float* ff_be  = (const float*)d_in[26];
  const float* ff_m   = (const float*)d_in[27];
  const float* ff_v   = (const float*)d_in[28];

  char* ws = (char*)d_ws;
  float* pe  = (float*)(ws + OFF_PE);
  u16*  w1b  = (u16*)(ws + OFF_W1);
  u16*  wk2  = (u16*)(ws + OFF_WK2);
  u16*  wff  = (u16*)(ws + OFF_WFF);
  u16*  wd2  = (u16*)(ws + OFF_WD2);
  float* b1  = (float*)(ws + OFF_B1);
  float* bk2 = (float*)(ws + OFF_BK2);
  float* bff = (float*)(ws + OFF_BFF);
  float* bd2 = (float*)(ws + OFF_BD2);
  float* attw= (float*)(ws + OFF_ATT);
  u16*  xb   = (u16*)(ws + OFF_XB);
  u16*  qkb  = (u16*)(ws + OFF_BIG);   // [128][1024][384]
  u16*  Pb   = (u16*)(ws + OFF_BIG);   // [128][800][768]  (after att done)
  u16*  y4b  = (u16*)(ws + OFF_BIG);   // [128][256][800]  (after G_k2 done)
  u16*  yb   = (u16*)(ws + OFF_Y3);    // [128][800][256]
  u16*  y3b  = (u16*)(ws + OFF_Y3);    // same region, after G_in done

  prep_k<<<256, 256, 0, stream>>>(
      in_w, in_b, out_w, out_b, d1_w, d1_b, d2_w, d2_b, ff_w, ff_b,
      out_g, out_be, out_m, out_v, d1_g, d1_be, d1_m, d1_v,
      d2_g, d2_be, d2_m, d2_v, ff_g, ff_be, ff_m, ff_v,
      pe, w1b, b1, wk2, bk2, wff, bff, wd2, bd2, qkb);

  k0_pe_cvt<<<dim3(TT, NB), 256, 0, stream>>>(x, pe, yb);

  // qk = in_w @ (x+pe) + in_b   -> qkb (padded pixel-major)
  gemm_k<256, 4, 256, 256, 0><<<dim3(5, 3, NB), 512, 0, stream>>>(w1b, b1, yb, yb, qkb, nullptr);

  att_k<<<dim3(SSS, NB), 64, 0, stream>>>(qkb, alphas, att0, attw);

  p_k<<<dim3(TT, NB), 256, 0, stream>>>(x, attw, Pb, xb);

  // y3 = lrelu( bn(out_w @ P) + bn(d1_w @ x) )   (K=1024 fused)
  gemm_k<1024, 12, 768, 256, 1><<<dim3(5, 2, NB), 512, 0, stream>>>(wk2, bk2, Pb, xb, y3b, nullptr);

  // y4 = lrelu( bn(ff_w @ y3) )
  gemm_k<256, 4, 256, 256, 2><<<dim3(5, 2, NB), 512, 0, stream>>>(wff, bff, y3b, y3b, y4b, nullptr);

  // out = lrelu( bn(d2_w @ x) + y4 )
  gemm_k<256, 4, 256, 256, 3><<<dim3(5, 2, NB), 512, 0, stream>>>(wd2, bd2, xb, xb, d_out, y4b);
}

// Round 5
// 685.473 us; speedup vs baseline: 1.0525x; 1.0525x over previous
//
#include <hip/hip_runtime.h>

typedef unsigned short u16;
typedef __bf16 bf16x8 __attribute__((ext_vector_type(8)));
typedef float f32x4 __attribute__((ext_vector_type(4)));

constexpr int NB = 128;   // batch
constexpr int CC = 256;   // channels
constexpr int TT = 32;
constexpr int VV = 25;
constexpr int SSS = 3;
constexpr int PIX = 800;  // T*V
constexpr float EPSV = 1e-5f;

// ---------------- workspace layout (bytes) ----------------
constexpr size_t OFF_PE  = 0;                        // 6400 f32
constexpr size_t OFF_W1  = 64*1024;                  // 384x256 bf16
constexpr size_t OFF_WK2 = OFF_W1  + 256*1024;       // 256x1024 bf16
constexpr size_t OFF_WFF = OFF_WK2 + 512*1024;       // 256x256 bf16
constexpr size_t OFF_WD2 = OFF_WFF + 128*1024;       // 256x256 bf16
constexpr size_t OFF_B1  = OFF_WD2 + 128*1024;       // 384 f32
constexpr size_t OFF_BK2 = OFF_B1  + 4096;           // 256 f32
constexpr size_t OFF_BFF = OFF_BK2 + 4096;
constexpr size_t OFF_BD2 = OFF_BFF + 4096;
constexpr size_t OFF_ATT = 2ull*1024*1024;           // attb [128][3][32][32] bf16 = 786,432 B
constexpr size_t OFF_XB  = 4ull*1024*1024;           // xb [128][800][256] bf16 = 52,428,800
constexpr size_t OFF_BIG = OFF_XB + 52428800ull;     // region: qkb [128][1024][384] (100.7MB) -> Pb [128][800][768] (157.3MB) -> y4b (52.4MB)
constexpr size_t OFF_Y3  = OFF_BIG + 157286400ull;   // region: yb then y3b [128][800][256] bf16

__device__ __forceinline__ float bf2f(u16 h) {
  union { unsigned u; float f; } c; c.u = ((unsigned)h) << 16; return c.f;
}
__device__ __forceinline__ u16 f2bf(float f) {
  union { float f; unsigned u; } c; c.f = f;
  unsigned r = c.u + 0x7fffu + ((c.u >> 16) & 1u);
  return (u16)(r >> 16);
}
__device__ __forceinline__ float lrelu(float z) { return z >= 0.f ? z : 0.1f*z; }

// ---------------- prep: fold BN into bf16 weights, PE table, pad-zero qkb ----------------
__global__ void prep_k(
    const float* __restrict__ in_w,  const float* __restrict__ in_b,
    const float* __restrict__ out_w, const float* __restrict__ out_b,
    const float* __restrict__ d1_w,  const float* __restrict__ d1_b,
    const float* __restrict__ d2_w,  const float* __restrict__ d2_b,
    const float* __restrict__ ff_w,  const float* __restrict__ ff_b,
    const float* __restrict__ out_g, const float* __restrict__ out_be, const float* __restrict__ out_m, const float* __restrict__ out_v,
    const float* __restrict__ d1_g,  const float* __restrict__ d1_be,  const float* __restrict__ d1_m,  const float* __restrict__ d1_v,
    const float* __restrict__ d2_g,  const float* __restrict__ d2_be,  const float* __restrict__ d2_m,  const float* __restrict__ d2_v,
    const float* __restrict__ ff_g,  const float* __restrict__ ff_be,  const float* __restrict__ ff_m,  const float* __restrict__ ff_v,
    float* __restrict__ pe, u16* __restrict__ w1b, float* __restrict__ b1,
    u16* __restrict__ wk2, float* __restrict__ bk2,
    u16* __restrict__ wff, float* __restrict__ bff,
    u16* __restrict__ wd2, float* __restrict__ bd2,
    u16* __restrict__ qkb)
{
  const int id  = blockIdx.x*blockDim.x + threadIdx.x;
  const int nth = gridDim.x*blockDim.x;
  // PE table: pe[ch][v]; ch=2j -> sin(v*div[j]), ch=2j+1 -> cos
  for (int i = id; i < CC*VV; i += nth) {
    int ch = i / VV, vv = i - ch*VV;
    int j = ch >> 1;
    float ang = (float)vv * expf((float)j * (-2.0f*logf(10000.0f)/(float)CC));
    pe[i] = (ch & 1) ? cosf(ang) : sinf(ang);
  }
  for (int i = id; i < 384*CC; i += nth) w1b[i] = f2bf(in_w[i]);
  for (int i = id; i < 384;    i += nth) b1[i] = in_b[i];
  // fused out-conv (k<768) + d1-conv (k>=768), both with BN folded
  for (int i = id; i < CC*1024; i += nth) {
    int o = i >> 10, k = i & 1023;
    float w;
    if (k < 768) { float inv = out_g[o]*rsqrtf(out_v[o]+EPSV); w = out_w[o*768+k]*inv; }
    else         { float inv = d1_g[o]*rsqrtf(d1_v[o]+EPSV);   w = d1_w[o*256+(k-768)]*inv; }
    wk2[i] = f2bf(w);
  }
  for (int i = id; i < CC*CC; i += nth) {
    int o = i >> 8;
    wff[i] = f2bf(ff_w[i]*(ff_g[o]*rsqrtf(ff_v[o]+EPSV)));
    wd2[i] = f2bf(d2_w[i]*(d2_g[o]*rsqrtf(d2_v[o]+EPSV)));
  }
  for (int i = id; i < CC; i += nth) {
    float invo = out_g[i]*rsqrtf(out_v[i]+EPSV);
    float invd = d1_g[i]*rsqrtf(d1_v[i]+EPSV);
    bk2[i] = out_b[i]*invo + out_be[i] - out_m[i]*invo
           + d1_b[i]*invd  + d1_be[i]  - d1_m[i]*invd;
    float invf = ff_g[i]*rsqrtf(ff_v[i]+EPSV);
    bff[i] = ff_b[i]*invf + ff_be[i] - ff_m[i]*invf;
    float inv2 = d2_g[i]*rsqrtf(d2_v[i]+EPSV);
    bd2[i] = d2_b[i]*inv2 + d2_be[i] - d2_m[i]*inv2;
  }
  // zero the pad rows (v=25..31) of qkb [n][t*32+v][384]
  for (int i = id; i < NB*TT*7*384; i += nth) {
    int ch = i % 384; int r = i / 384;
    int pr = r % 7; int t = (r/7) % TT; int n = r / (7*TT);
    qkb[((size_t)n*1024 + (size_t)t*32 + 25 + pr)*384 + ch] = 0;
  }
}

// ---------------- k0: yb[n][p][c] = bf16(x + pe); xb[n][p][c] = bf16(x) ----------------
__global__ __launch_bounds__(256) void k0_pe_cvt(
    const float* __restrict__ x, const float* __restrict__ pe,
    u16* __restrict__ yb, u16* __restrict__ xb)
{
  __shared__ float xt[CC*VV];
  __shared__ float pl[CC*VV];
  const int t = blockIdx.x, n = blockIdx.y;
  const float* xs = x + (size_t)n*CC*PIX + t*VV;
  for (int f = threadIdx.x; f < CC*VV; f += 256) {
    int c = f / VV, u = f - c*VV;
    xt[f] = xs[(size_t)c*PIX + u];
    pl[f] = pe[f];
  }
  __syncthreads();
  const int c = threadIdx.x;
  u16* yrow = yb + ((size_t)n*PIX + t*VV)*CC + c;
  u16* xrow = xb + ((size_t)n*PIX + t*VV)*CC + c;
  #pragma unroll
  for (int u = 0; u < VV; ++u) {
    float xv = xt[c*VV+u];
    yrow[(size_t)u*CC] = f2bf(xv + pl[c*VV+u]);
    xrow[(size_t)u*CC] = f2bf(xv);
  }
}

// ---------------- att: per (n,s) 1-wave MFMA Q^T K, tanh epilogue -> attb[v][u] bf16 ----------------
// attb [n][s][v:32][u:32] = att^T, zero-padded (B-operand-ready, k(=u)-contiguous)
__global__ __launch_bounds__(64) void att_k(
    const u16* __restrict__ qkb, const float* __restrict__ alphas,
    const float* __restrict__ att0, u16* __restrict__ attb)
{
  const int s = blockIdx.x, n = blockIdx.y, lane = threadIdx.x;
  const u16* qb = qkb + (size_t)n*1024*384 + s*64;
  const u16* kb = qb + 192;   // k channels start at 3*64
  f32x4 acc[2][2];
  #pragma unroll
  for (int i = 0; i < 2; ++i)
    #pragma unroll
    for (int j = 0; j < 2; ++j) acc[i][j] = f32x4{0.f,0.f,0.f,0.f};

  for (int t = 0; t < TT; ++t) {
    const u16* qrow = qb + (size_t)t*32*384;
    const u16* krow = kb + (size_t)t*32*384;
    #pragma unroll
    for (int ks = 0; ks < 2; ++ks) {
      const int ko = ks*32 + (lane>>4)*8;
      bf16x8 a0 = *(const bf16x8*)(qrow + (size_t)(lane&15)*384 + ko);
      bf16x8 a1 = *(const bf16x8*)(qrow + (size_t)(16+(lane&15))*384 + ko);
      bf16x8 b0 = *(const bf16x8*)(krow + (size_t)(lane&15)*384 + ko);
      bf16x8 b1 = *(const bf16x8*)(krow + (size_t)(16+(lane&15))*384 + ko);
      acc[0][0] = __builtin_amdgcn_mfma_f32_16x16x32_bf16(a0, b0, acc[0][0], 0,0,0);
      acc[0][1] = __builtin_amdgcn_mfma_f32_16x16x32_bf16(a0, b1, acc[0][1], 0,0,0);
      acc[1][0] = __builtin_amdgcn_mfma_f32_16x16x32_bf16(a1, b0, acc[1][0], 0,0,0);
      acc[1][1] = __builtin_amdgcn_mfma_f32_16x16x32_bf16(a1, b1, acc[1][1], 0,0,0);
    }
  }
  const float alpha = alphas[s];
  const float sc = 1.0f/2048.0f;
  u16* ab = attb + ((size_t)n*SSS + s)*1024;   // [v:32][u:32]
  #pragma unroll
  for (int fm = 0; fm < 2; ++fm)
    #pragma unroll
    for (int fn = 0; fn < 2; ++fn)
      #pragma unroll
      for (int j = 0; j < 4; ++j) {
        int u = fm*16 + (lane>>4)*4 + j;   // q index (row of att)
        int v = fn*16 + (lane&15);         // k index (col of att)
        float val = 0.f;
        if (u < VV && v < VV)
          val = tanhf(acc[fm][fn][j]*sc)*alpha + att0[s*VV*VV + u*VV + v];
        ab[v*32 + u] = f2bf(val);          // transposed store
      }
}

// ---------------- p_k2: Pb[n][p][s*256+c] = sum_u x[c][u]*att[u][v] via MFMA ----------------
// Per (n,t): M=256(c) x N=32(v,pad) x K=32(u,pad) per s. LDS rows padded to 40 elems (80B)
// -> ds_read_b128 banks spread over 8 groups (2-way, free per m136).
__global__ __launch_bounds__(256) void p_k2(
    const float* __restrict__ x, const u16* __restrict__ attb, u16* __restrict__ Pb)
{
  __shared__ u16 Xs[CC*40];       // [c:256][u:40]  20,480 B
  __shared__ u16 Al[SSS*32*40];   // [s][v:32][u:40] 7,680 B
  const int t = blockIdx.x, n = blockIdx.y;
  const float* xs = x + (size_t)n*CC*PIX + t*VV;
  for (int f = threadIdx.x; f < CC*VV; f += 256) {
    int c = f / VV, u = f - c*VV;
    Xs[c*40+u] = f2bf(xs[(size_t)c*PIX + u]);
  }
  for (int idx = threadIdx.x; idx < CC*7; idx += 256) {
    int c = idx / 7, u = 25 + idx % 7;
    Xs[c*40+u] = 0;               // zero K-pad u=25..31
  }
  const u16* ab = attb + (size_t)n*SSS*1024;
  for (int f = threadIdx.x; f < SSS*1024; f += 256) {
    int sv = f >> 5, u = f & 31;
    Al[sv*40+u] = ab[f];
  }
  __syncthreads();

  const int lane = threadIdx.x & 63, w = threadIdx.x >> 6;
  const int cb0 = w*64;                 // wave's 64-channel slab
  const int k0 = (lane>>4)*8;
  const int r15 = lane & 15;
  f32x4 acc[SSS][4][2];
  #pragma unroll
  for (int s = 0; s < SSS; ++s)
    #pragma unroll
    for (int mt = 0; mt < 4; ++mt)
      #pragma unroll
      for (int nt = 0; nt < 2; ++nt) acc[s][mt][nt] = f32x4{0.f,0.f,0.f,0.f};

  #pragma unroll
  for (int s = 0; s < SSS; ++s) {
    bf16x8 b0 = *(const bf16x8*)&Al[((s*32) + r15)*40 + k0];
    bf16x8 b1 = *(const bf16x8*)&Al[((s*32) + 16 + r15)*40 + k0];
    #pragma unroll
    for (int mt = 0; mt < 4; ++mt) {
      bf16x8 a = *(const bf16x8*)&Xs[(cb0 + mt*16 + r15)*40 + k0];
      acc[s][mt][0] = __builtin_amdgcn_mfma_f32_16x16x32_bf16(a, b0, acc[s][mt][0], 0,0,0);
      acc[s][mt][1] = __builtin_amdgcn_mfma_f32_16x16x32_bf16(a, b1, acc[s][mt][1], 0,0,0);
    }
  }

  const int j4 = (lane>>4)*4;
  #pragma unroll
  for (int s = 0; s < SSS; ++s)
    #pragma unroll
    for (int nt = 0; nt < 2; ++nt) {
      const int v = nt*16 + r15;
      if (v < VV) {
        u16* dst0 = Pb + ((size_t)n*PIX + t*VV + v)*768 + s*CC + cb0 + j4;
        #pragma unroll
        for (int mt = 0; mt < 4; ++mt) {
          f32x4 a = acc[s][mt][nt];
          ushort4 st; st.x=f2bf(a[0]); st.y=f2bf(a[1]); st.z=f2bf(a[2]); st.w=f2bf(a[3]);
          *(ushort4*)(dst0 + mt*16) = st;
        }
      }
    }
}

// ---------------- GEMM: OUT[o, p] = W[o,:] . Bpm[p,:] + bias, per-n ----------------
// m97-style: 2-barrier dbuf, global_load_lds width 16. Block tile 128x160, 8 waves (4Mx2N),
// wave tile 32x80, 16x16x32 bf16 MFMA.
// EPI: 0 = store bf16 to qkb [n][ (p/25)*32+p%25 ][384] (padded-row layout)
//      1 = lrelu, store bf16 pixel-major [n][p][256]
//      2 = lrelu, store bf16 chan-major [n][256][800]
//      3 = +y4b, lrelu, store f32 chan-major [n][256][800]
template<int KTOT, int NKC0, int BS0, int BS1, int EPI>
__global__ __launch_bounds__(512, 1)
void gemm_k(const u16* __restrict__ W, const float* __restrict__ bias,
            const u16* __restrict__ B0, const u16* __restrict__ B1,
            void* __restrict__ outv, const u16* __restrict__ y4b)
{
  constexpr int NKC = KTOT/64;
  __shared__ u16 As[2][128*64];
  __shared__ u16 Bs[2][160*64];
  const int tid = threadIdx.x;
  const int lane = tid & 63, wid = tid >> 6;
  const int wm = wid >> 1, wn = wid & 1;
  const int pt = blockIdx.x, mt = blockIdx.y, n = blockIdx.z;
  const int m0 = mt*128, p0 = pt*160;
  const int lr = lane >> 3;        // 0..7
  const int lc = (lane & 7) * 8;   // element offset within 64-wide k chunk

  f32x4 acc[2][5];
  #pragma unroll
  for (int i = 0; i < 2; ++i)
    #pragma unroll
    for (int j = 0; j < 5; ++j) acc[i][j] = f32x4{0.f,0.f,0.f,0.f};

  auto stage = [&](int buf, int kc) {
    const u16* wsrc = W + (size_t)m0*KTOT + (size_t)kc*64;
    for (int g = wid; g < 16; g += 8) {
      const u16* src = wsrc + (size_t)(g*8 + lr)*KTOT + lc;
      __builtin_amdgcn_global_load_lds(
          (const __attribute__((address_space(1))) void*)src,
          (__attribute__((address_space(3))) void*)(&As[buf][g*512]), 16, 0, 0);
    }
    const u16* bbase; int bs;
    if (NKC0 >= NKC || kc < NKC0) {
      bbase = B0 + ((size_t)n*PIX + p0)*BS0 + (size_t)kc*64; bs = BS0;
    } else {
      bbase = B1 + ((size_t)n*PIX + p0)*BS1 + (size_t)(kc-NKC0)*64; bs = BS1;
    }
    for (int g = wid; g < 20; g += 8) {
      const u16* src = bbase + (size_t)(g*8 + lr)*bs + lc;
      __builtin_amdgcn_global_load_lds(
          (const __attribute__((address_space(1))) void*)src,
          (__attribute__((address_space(3))) void*)(&Bs[buf][g*512]), 16, 0, 0);
    }
  };

  auto compute = [&](int buf) {
    #pragma unroll
    for (int ks = 0; ks < 2; ++ks) {
      const int ko = ks*32 + (lane>>4)*8;
      bf16x8 a0 = *(const bf16x8*)&As[buf][(wm*32 + (lane&15))*64 + ko];
      bf16x8 a1 = *(const bf16x8*)&As[buf][(wm*32 + 16 + (lane&15))*64 + ko];
      bf16x8 bfr[5];
      #pragma unroll
      for (int fn = 0; fn < 5; ++fn)
        bfr[fn] = *(const bf16x8*)&Bs[buf][(wn*80 + fn*16 + (lane&15))*64 + ko];
      #pragma unroll
      for (int fn = 0; fn < 5; ++fn) {
        acc[0][fn] = __builtin_amdgcn_mfma_f32_16x16x32_bf16(a0, bfr[fn], acc[0][fn], 0,0,0);
        acc[1][fn] = __builtin_amdgcn_mfma_f32_16x16x32_bf16(a1, bfr[fn], acc[1][fn], 0,0,0);
      }
    }
  };

  stage(0, 0);
  __syncthreads();
  for (int kc = 0; kc < NKC; ++kc) {
    if (kc + 1 < NKC) stage((kc+1)&1, kc+1);
    compute(kc&1);
    __syncthreads();
  }

  // epilogue
  const int oc = (lane>>4)*4, pc = lane&15;
  #pragma unroll
  for (int fm = 0; fm < 2; ++fm) {
    const int o = m0 + wm*32 + fm*16 + oc;
    const float4 bv = *(const float4*)&bias[o];
    #pragma unroll
    for (int fn = 0; fn < 5; ++fn) {
      const int p = p0 + wn*80 + fn*16 + pc;
      f32x4 v = acc[fm][fn];
      float r0 = v[0]+bv.x, r1 = v[1]+bv.y, r2 = v[2]+bv.z, r3 = v[3]+bv.w;
      if constexpr (EPI == 0) {
        int row = (p/VV)*32 + (p%VV);
        ushort4 st; st.x=f2bf(r0); st.y=f2bf(r1); st.z=f2bf(r2); st.w=f2bf(r3);
        *(ushort4*)((u16*)outv + ((size_t)n*1024 + row)*384 + o) = st;
      } else if constexpr (EPI == 1) {
        ushort4 st;
        st.x=f2bf(lrelu(r0)); st.y=f2bf(lrelu(r1)); st.z=f2bf(lrelu(r2)); st.w=f2bf(lrelu(r3));
        *(ushort4*)((u16*)outv + ((size_t)n*PIX + p)*256 + o) = st;
      } else if constexpr (EPI == 2) {
        u16* op = (u16*)outv + ((size_t)n*256 + o)*PIX + p;
        op[0]      = f2bf(lrelu(r0));
        op[PIX]    = f2bf(lrelu(r1));
        op[2*PIX]  = f2bf(lrelu(r2));
        op[3*PIX]  = f2bf(lrelu(r3));
      } else {
        const u16* yp = y4b + ((size_t)n*256 + o)*PIX + p;
        float* op = (float*)outv + ((size_t)n*256 + o)*PIX + p;
        op[0]      = lrelu(r0 + bf2f(yp[0]));
        op[PIX]    = lrelu(r1 + bf2f(yp[PIX]));
        op[2*PIX]  = lrelu(r2 + bf2f(yp[2*PIX]));
        op[3*PIX]  = lrelu(r3 + bf2f(yp[3*PIX]));
      }
    }
  }
}

extern "C" void kernel_launch(void* const* d_in, const int* in_sizes, int n_in,
                              void* d_out, int out_size, void* d_ws, size_t ws_size,
                              hipStream_t stream)
{
  const float* x      = (const float*)d_in[0];
  const float* in_w   = (const float*)d_in[1];
  const float* in_b   = (const float*)d_in[2];
  const float* alphas = (const float*)d_in[3];
  const float* att0   = (const float*)d_in[4];
  const float* out_w  = (const float*)d_in[5];
  const float* out_b  = (const float*)d_in[6];
  const float* d1_w   = (const float*)d_in[7];
  const float* d1_b   = (const float*)d_in[8];
  const float* d2_w   = (const float*)d_in[9];
  const float* d2_b   = (const float*)d_in[10];
  const float* ff_w   = (const float*)d_in[11];
  const float* ff_b   = (const float*)d_in[12];
  const float* out_g  = (const float*)d_in[13];
  const float* out_be = (const float*)d_in[14];
  const float* out_m  = (const float*)d_in[15];
  const float* out_v  = (const float*)d_in[16];
  const float* d1_g   = (const float*)d_in[17];
  const float* d1_be  = (const float*)d_in[18];
  const float* d1_m   = (const float*)d_in[19];
  const float* d1_v   = (const float*)d_in[20];
  const float* d2_g   = (const float*)d_in[21];
  const float* d2_be  = (const float*)d_in[22];
  const float* d2_m   = (const float*)d_in[23];
  const float* d2_v   = (const float*)d_in[24];
  const float* ff_g   = (const float*)d_in[25];
  const float* ff_be  = (const float*)d_in[26];
  const float* ff_m   = (const float*)d_in[27];
  const float* ff_v   = (const float*)d_in[28];

  char* ws = (char*)d_ws;
  float* pe  = (float*)(ws + OFF_PE);
  u16*  w1b  = (u16*)(ws + OFF_W1);
  u16*  wk2  = (u16*)(ws + OFF_WK2);
  u16*  wff  = (u16*)(ws + OFF_WFF);
  u16*  wd2  = (u16*)(ws + OFF_WD2);
  float* b1  = (float*)(ws + OFF_B1);
  float* bk2 = (float*)(ws + OFF_BK2);
  float* bff = (float*)(ws + OFF_BFF);
  float* bd2 = (float*)(ws + OFF_BD2);
  u16*  attb = (u16*)(ws + OFF_ATT);
  u16*  xb   = (u16*)(ws + OFF_XB);
  u16*  qkb  = (u16*)(ws + OFF_BIG);   // [128][1024][384]
  u16*  Pb   = (u16*)(ws + OFF_BIG);   // [128][800][768]  (after att done)
  u16*  y4b  = (u16*)(ws + OFF_BIG);   // [128][256][800]  (after G_k2 done)
  u16*  yb   = (u16*)(ws + OFF_Y3);    // [128][800][256]
  u16*  y3b  = (u16*)(ws + OFF_Y3);    // same region, after G_in done

  prep_k<<<256, 256, 0, stream>>>(
      in_w, in_b, out_w, out_b, d1_w, d1_b, d2_w, d2_b, ff_w, ff_b,
      out_g, out_be, out_m, out_v, d1_g, d1_be, d1_m, d1_v,
      d2_g, d2_be, d2_m, d2_v, ff_g, ff_be, ff_m, ff_v,
      pe, w1b, b1, wk2, bk2, wff, bff, wd2, bd2, qkb);

  k0_pe_cvt<<<dim3(TT, NB), 256, 0, stream>>>(x, pe, yb, xb);

  // qk = in_w @ (x+pe) + in_b   -> qkb (padded pixel-major)
  gemm_k<256, 4, 256, 256, 0><<<dim3(5, 3, NB), 512, 0, stream>>>(w1b, b1, yb, yb, qkb, nullptr);

  att_k<<<dim3(SSS, NB), 64, 0, stream>>>(qkb, alphas, att0, attb);

  p_k2<<<dim3(TT, NB), 256, 0, stream>>>(x, attb, Pb);

  // y3 = lrelu( bn(out_w @ P) + bn(d1_w @ x) )   (K=1024 fused)
  gemm_k<1024, 12, 768, 256, 1><<<dim3(5, 2, NB), 512, 0, stream>>>(wk2, bk2, Pb, xb, y3b, nullptr);

  // y4 = lrelu( bn(ff_w @ y3) )
  gemm_k<256, 4, 256, 256, 2><<<dim3(5, 2, NB), 512, 0, stream>>>(wff, bff, y3b, y3b, y4b, nullptr);

  // out = lrelu( bn(d2_w @ x) + y4 )
  gemm_k<256, 4, 256, 256, 3><<<dim3(5, 2, NB), 512, 0, stream>>>(wd2, bd2, xb, xb, d_out, y4b);
}

// Round 6
// 640.023 us; speedup vs baseline: 1.1272x; 1.0710x over previous
//
#include <hip/hip_runtime.h>

typedef unsigned short u16;
typedef __bf16 bf16x8 __attribute__((ext_vector_type(8)));
typedef float f32x4 __attribute__((ext_vector_type(4)));

constexpr int NB = 128;   // batch
constexpr int CC = 256;   // channels
constexpr int TT = 32;
constexpr int VV = 25;
constexpr int SSS = 3;
constexpr int PIX = 800;  // T*V
constexpr float EPSV = 1e-5f;

// ---------------- workspace layout (bytes) ----------------
constexpr size_t OFF_PE  = 0;                        // 6400 f32
constexpr size_t OFF_W1  = 64*1024;                  // 384x256 bf16
constexpr size_t OFF_WK2 = OFF_W1  + 256*1024;       // 256x1024 bf16
constexpr size_t OFF_WFF = OFF_WK2 + 512*1024;       // 256x256 bf16
constexpr size_t OFF_WD2 = OFF_WFF + 128*1024;       // 256x256 bf16
constexpr size_t OFF_B1  = OFF_WD2 + 128*1024;       // 384 f32
constexpr size_t OFF_BK2 = OFF_B1  + 4096;           // 256 f32
constexpr size_t OFF_BFF = OFF_BK2 + 4096;
constexpr size_t OFF_BD2 = OFF_BFF + 4096;
constexpr size_t OFF_ATT = 2ull*1024*1024;           // attb [128][3][32][32] bf16 = 786,432 B
constexpr size_t OFF_XB  = 4ull*1024*1024;           // xb [128][800][256] bf16 = 52,428,800
constexpr size_t OFF_BIG = OFF_XB + 52428800ull;     // region: qkb [128][1024][384] (100.7MB) -> Pb [128][800][768] (157.3MB) -> y4b (52.4MB)
constexpr size_t OFF_Y3  = OFF_BIG + 157286400ull;   // region: yb then y3b [128][800][256] bf16

__device__ __forceinline__ float bf2f(u16 h) {
  union { unsigned u; float f; } c; c.u = ((unsigned)h) << 16; return c.f;
}
__device__ __forceinline__ u16 f2bf(float f) {
  union { float f; unsigned u; } c; c.f = f;
  unsigned r = c.u + 0x7fffu + ((c.u >> 16) & 1u);
  return (u16)(r >> 16);
}
__device__ __forceinline__ float lrelu(float z) { return z >= 0.f ? z : 0.1f*z; }

// ---------------- prep: fold BN into bf16 weights, PE table, pad-zero qkb ----------------
__global__ void prep_k(
    const float* __restrict__ in_w,  const float* __restrict__ in_b,
    const float* __restrict__ out_w, const float* __restrict__ out_b,
    const float* __restrict__ d1_w,  const float* __restrict__ d1_b,
    const float* __restrict__ d2_w,  const float* __restrict__ d2_b,
    const float* __restrict__ ff_w,  const float* __restrict__ ff_b,
    const float* __restrict__ out_g, const float* __restrict__ out_be, const float* __restrict__ out_m, const float* __restrict__ out_v,
    const float* __restrict__ d1_g,  const float* __restrict__ d1_be,  const float* __restrict__ d1_m,  const float* __restrict__ d1_v,
    const float* __restrict__ d2_g,  const float* __restrict__ d2_be,  const float* __restrict__ d2_m,  const float* __restrict__ d2_v,
    const float* __restrict__ ff_g,  const float* __restrict__ ff_be,  const float* __restrict__ ff_m,  const float* __restrict__ ff_v,
    float* __restrict__ pe, u16* __restrict__ w1b, float* __restrict__ b1,
    u16* __restrict__ wk2, float* __restrict__ bk2,
    u16* __restrict__ wff, float* __restrict__ bff,
    u16* __restrict__ wd2, float* __restrict__ bd2,
    u16* __restrict__ qkb)
{
  const int id  = blockIdx.x*blockDim.x + threadIdx.x;
  const int nth = gridDim.x*blockDim.x;
  // PE table: pe[ch][v]; ch=2j -> sin(v*div[j]), ch=2j+1 -> cos
  for (int i = id; i < CC*VV; i += nth) {
    int ch = i / VV, vv = i - ch*VV;
    int j = ch >> 1;
    float ang = (float)vv * expf((float)j * (-2.0f*logf(10000.0f)/(float)CC));
    pe[i] = (ch & 1) ? cosf(ang) : sinf(ang);
  }
  for (int i = id; i < 384*CC; i += nth) w1b[i] = f2bf(in_w[i]);
  for (int i = id; i < 384;    i += nth) b1[i] = in_b[i];
  // fused out-conv (k<768) + d1-conv (k>=768), both with BN folded
  for (int i = id; i < CC*1024; i += nth) {
    int o = i >> 10, k = i & 1023;
    float w;
    if (k < 768) { float inv = out_g[o]*rsqrtf(out_v[o]+EPSV); w = out_w[o*768+k]*inv; }
    else         { float inv = d1_g[o]*rsqrtf(d1_v[o]+EPSV);   w = d1_w[o*256+(k-768)]*inv; }
    wk2[i] = f2bf(w);
  }
  for (int i = id; i < CC*CC; i += nth) {
    int o = i >> 8;
    wff[i] = f2bf(ff_w[i]*(ff_g[o]*rsqrtf(ff_v[o]+EPSV)));
    wd2[i] = f2bf(d2_w[i]*(d2_g[o]*rsqrtf(d2_v[o]+EPSV)));
  }
  for (int i = id; i < CC; i += nth) {
    float invo = out_g[i]*rsqrtf(out_v[i]+EPSV);
    float invd = d1_g[i]*rsqrtf(d1_v[i]+EPSV);
    bk2[i] = out_b[i]*invo + out_be[i] - out_m[i]*invo
           + d1_b[i]*invd  + d1_be[i]  - d1_m[i]*invd;
    float invf = ff_g[i]*rsqrtf(ff_v[i]+EPSV);
    bff[i] = ff_b[i]*invf + ff_be[i] - ff_m[i]*invf;
    float inv2 = d2_g[i]*rsqrtf(d2_v[i]+EPSV);
    bd2[i] = d2_b[i]*inv2 + d2_be[i] - d2_m[i]*inv2;
  }
  // zero the pad rows (v=25..31) of qkb [n][t*32+v][384]
  for (int i = id; i < NB*TT*7*384; i += nth) {
    int ch = i % 384; int r = i / 384;
    int pr = r % 7; int t = (r/7) % TT; int n = r / (7*TT);
    qkb[((size_t)n*1024 + (size_t)t*32 + 25 + pr)*384 + ch] = 0;
  }
}

// ---------------- k0: yb[n][p][c] = bf16(x + pe); xb[n][p][c] = bf16(x) ----------------
__global__ __launch_bounds__(256) void k0_pe_cvt(
    const float* __restrict__ x, const float* __restrict__ pe,
    u16* __restrict__ yb, u16* __restrict__ xb)
{
  __shared__ float xt[CC*VV];
  __shared__ float pl[CC*VV];
  const int t = blockIdx.x, n = blockIdx.y;
  const float* xs = x + (size_t)n*CC*PIX + t*VV;
  for (int f = threadIdx.x; f < CC*VV; f += 256) {
    int c = f / VV, u = f - c*VV;
    xt[f] = xs[(size_t)c*PIX + u];
    pl[f] = pe[f];
  }
  __syncthreads();
  const int c = threadIdx.x;
  u16* yrow = yb + ((size_t)n*PIX + t*VV)*CC + c;
  u16* xrow = xb + ((size_t)n*PIX + t*VV)*CC + c;
  #pragma unroll
  for (int u = 0; u < VV; ++u) {
    float xv = xt[c*VV+u];
    yrow[(size_t)u*CC] = f2bf(xv + pl[c*VV+u]);
    xrow[(size_t)u*CC] = f2bf(xv);
  }
}

// ---------------- att: per (n,s) 1-wave MFMA Q^T K, tanh epilogue -> attb[v][u] bf16 ----------------
// attb [n][s][v:32][u:32] = att^T, zero-padded (B-operand-ready, k(=u)-contiguous)
__global__ __launch_bounds__(64) void att_k(
    const u16* __restrict__ qkb, const float* __restrict__ alphas,
    const float* __restrict__ att0, u16* __restrict__ attb)
{
  const int s = blockIdx.x, n = blockIdx.y, lane = threadIdx.x;
  const u16* qb = qkb + (size_t)n*1024*384 + s*64;
  const u16* kb = qb + 192;   // k channels start at 3*64
  f32x4 acc[2][2];
  #pragma unroll
  for (int i = 0; i < 2; ++i)
    #pragma unroll
    for (int j = 0; j < 2; ++j) acc[i][j] = f32x4{0.f,0.f,0.f,0.f};

  for (int t = 0; t < TT; ++t) {
    const u16* qrow = qb + (size_t)t*32*384;
    const u16* krow = kb + (size_t)t*32*384;
    #pragma unroll
    for (int ks = 0; ks < 2; ++ks) {
      const int ko = ks*32 + (lane>>4)*8;
      bf16x8 a0 = *(const bf16x8*)(qrow + (size_t)(lane&15)*384 + ko);
      bf16x8 a1 = *(const bf16x8*)(qrow + (size_t)(16+(lane&15))*384 + ko);
      bf16x8 b0 = *(const bf16x8*)(krow + (size_t)(lane&15)*384 + ko);
      bf16x8 b1 = *(const bf16x8*)(krow + (size_t)(16+(lane&15))*384 + ko);
      acc[0][0] = __builtin_amdgcn_mfma_f32_16x16x32_bf16(a0, b0, acc[0][0], 0,0,0);
      acc[0][1] = __builtin_amdgcn_mfma_f32_16x16x32_bf16(a0, b1, acc[0][1], 0,0,0);
      acc[1][0] = __builtin_amdgcn_mfma_f32_16x16x32_bf16(a1, b0, acc[1][0], 0,0,0);
      acc[1][1] = __builtin_amdgcn_mfma_f32_16x16x32_bf16(a1, b1, acc[1][1], 0,0,0);
    }
  }
  const float alpha = alphas[s];
  const float sc = 1.0f/2048.0f;
  u16* ab = attb + ((size_t)n*SSS + s)*1024;   // [v:32][u:32]
  #pragma unroll
  for (int fm = 0; fm < 2; ++fm)
    #pragma unroll
    for (int fn = 0; fn < 2; ++fn)
      #pragma unroll
      for (int j = 0; j < 4; ++j) {
        int u = fm*16 + (lane>>4)*4 + j;   // q index (row of att)
        int v = fn*16 + (lane&15);         // k index (col of att)
        float val = 0.f;
        if (u < VV && v < VV)
          val = tanhf(acc[fm][fn][j]*sc)*alpha + att0[s*VV*VV + u*VV + v];
        ab[v*32 + u] = f2bf(val);          // transposed store
      }
}

// ---------------- p_k2: Pb[n][p][s*256+c] = sum_u x[c][u]*att[u][v] via MFMA ----------------
// Per (n,t): M=256(c) x N=32(v,pad) x K=32(u,pad) per s. LDS rows padded to 40 elems (80B)
// -> banks spread (2-way, free per m136).
__global__ __launch_bounds__(256) void p_k2(
    const float* __restrict__ x, const u16* __restrict__ attb, u16* __restrict__ Pb)
{
  __shared__ u16 Xs[CC*40];       // [c:256][u:40]  20,480 B
  __shared__ u16 Al[SSS*32*40];   // [s][v:32][u:40] 7,680 B
  const int t = blockIdx.x, n = blockIdx.y;
  const float* xs = x + (size_t)n*CC*PIX + t*VV;
  for (int f = threadIdx.x; f < CC*VV; f += 256) {
    int c = f / VV, u = f - c*VV;
    Xs[c*40+u] = f2bf(xs[(size_t)c*PIX + u]);
  }
  for (int idx = threadIdx.x; idx < CC*7; idx += 256) {
    int c = idx / 7, u = 25 + idx % 7;
    Xs[c*40+u] = 0;               // zero K-pad u=25..31
  }
  const u16* ab = attb + (size_t)n*SSS*1024;
  for (int f = threadIdx.x; f < SSS*1024; f += 256) {
    int sv = f >> 5, u = f & 31;
    Al[sv*40+u] = ab[f];
  }
  __syncthreads();

  const int lane = threadIdx.x & 63, w = threadIdx.x >> 6;
  const int cb0 = w*64;                 // wave's 64-channel slab
  const int k0 = (lane>>4)*8;
  const int r15 = lane & 15;
  f32x4 acc[SSS][4][2];
  #pragma unroll
  for (int s = 0; s < SSS; ++s)
    #pragma unroll
    for (int mt = 0; mt < 4; ++mt)
      #pragma unroll
      for (int nt = 0; nt < 2; ++nt) acc[s][mt][nt] = f32x4{0.f,0.f,0.f,0.f};

  #pragma unroll
  for (int s = 0; s < SSS; ++s) {
    bf16x8 b0 = *(const bf16x8*)&Al[((s*32) + r15)*40 + k0];
    bf16x8 b1 = *(const bf16x8*)&Al[((s*32) + 16 + r15)*40 + k0];
    #pragma unroll
    for (int mt = 0; mt < 4; ++mt) {
      bf16x8 a = *(const bf16x8*)&Xs[(cb0 + mt*16 + r15)*40 + k0];
      acc[s][mt][0] = __builtin_amdgcn_mfma_f32_16x16x32_bf16(a, b0, acc[s][mt][0], 0,0,0);
      acc[s][mt][1] = __builtin_amdgcn_mfma_f32_16x16x32_bf16(a, b1, acc[s][mt][1], 0,0,0);
    }
  }

  const int j4 = (lane>>4)*4;
  #pragma unroll
  for (int s = 0; s < SSS; ++s)
    #pragma unroll
    for (int nt = 0; nt < 2; ++nt) {
      const int v = nt*16 + r15;
      if (v < VV) {
        u16* dst0 = Pb + ((size_t)n*PIX + t*VV + v)*768 + s*CC + cb0 + j4;
        #pragma unroll
        for (int mt = 0; mt < 4; ++mt) {
          f32x4 a = acc[s][mt][nt];
          ushort4 st; st.x=f2bf(a[0]); st.y=f2bf(a[1]); st.z=f2bf(a[2]); st.w=f2bf(a[3]);
          *(ushort4*)(dst0 + mt*16) = st;
        }
      }
    }
}

// ---------------- GEMM: OUT[o, p] = W[o,:] . Bpm[p,:] + bias, per-n ----------------
// m97-style 2-barrier dbuf + T2 XOR-swizzle (rule #21: linear LDS dest for
// global_load_lds, INVERSE-swizzled global source, swizzled ds_read).
// Swizzle: 16B slot s within a 64-elem (128B) row lives at slot s^(row&7).
//   stage:  source slot = (lane&7) ^ lr    (row = g*8+lr, so row&7 == lr)
//   read:   slot = (ks*4 + lane>>4) ^ (lane&7)  (all fragment rows have row&7 == lane&7)
// Block tile 128x160, 8 waves (4Mx2N), wave tile 32x80, 16x16x32 bf16 MFMA.
// EPI: 0 = store bf16 to qkb [n][ (p/25)*32+p%25 ][384] (padded-row layout)
//      1 = lrelu, store bf16 pixel-major [n][p][256]
//      2 = lrelu, store bf16 chan-major [n][256][800]
//      3 = +y4b, lrelu, store f32 chan-major [n][256][800]
template<int KTOT, int NKC0, int BS0, int BS1, int EPI>
__global__ __launch_bounds__(512, 1)
void gemm_k(const u16* __restrict__ W, const float* __restrict__ bias,
            const u16* __restrict__ B0, const u16* __restrict__ B1,
            void* __restrict__ outv, const u16* __restrict__ y4b)
{
  constexpr int NKC = KTOT/64;
  __shared__ u16 As[2][128*64];
  __shared__ u16 Bs[2][160*64];
  const int tid = threadIdx.x;
  const int lane = tid & 63, wid = tid >> 6;
  const int wm = wid >> 1, wn = wid & 1;
  const int pt = blockIdx.x, mt = blockIdx.y, n = blockIdx.z;
  const int m0 = mt*128, p0 = pt*160;
  const int lr = lane >> 3;                      // 0..7 (== row&7 of this lane's dest row)
  const int lc = (((lane & 7) ^ lr)) * 8;        // inverse-swizzled source slot

  f32x4 acc[2][5];
  #pragma unroll
  for (int i = 0; i < 2; ++i)
    #pragma unroll
    for (int j = 0; j < 5; ++j) acc[i][j] = f32x4{0.f,0.f,0.f,0.f};

  auto stage = [&](int buf, int kc) {
    const u16* wsrc = W + (size_t)m0*KTOT + (size_t)kc*64;
    for (int g = wid; g < 16; g += 8) {
      const u16* src = wsrc + (size_t)(g*8 + lr)*KTOT + lc;
      __builtin_amdgcn_global_load_lds(
          (const __attribute__((address_space(1))) void*)src,
          (__attribute__((address_space(3))) void*)(&As[buf][g*512]), 16, 0, 0);
    }
    const u16* bbase; int bs;
    if (NKC0 >= NKC || kc < NKC0) {
      bbase = B0 + ((size_t)n*PIX + p0)*BS0 + (size_t)kc*64; bs = BS0;
    } else {
      bbase = B1 + ((size_t)n*PIX + p0)*BS1 + (size_t)(kc-NKC0)*64; bs = BS1;
    }
    for (int g = wid; g < 20; g += 8) {
      const u16* src = bbase + (size_t)(g*8 + lr)*bs + lc;
      __builtin_amdgcn_global_load_lds(
          (const __attribute__((address_space(1))) void*)src,
          (__attribute__((address_space(3))) void*)(&Bs[buf][g*512]), 16, 0, 0);
    }
  };

  auto compute = [&](int buf) {
    const int par = lane & 7;
    const int gq  = lane >> 4;
    const int r15 = lane & 15;
    #pragma unroll
    for (int ks = 0; ks < 2; ++ks) {
      const int ko = (((ks*4 + gq) ^ par)) * 8;  // swizzled 16B-slot read
      bf16x8 a0 = *(const bf16x8*)&As[buf][(wm*32 + r15)*64 + ko];
      bf16x8 a1 = *(const bf16x8*)&As[buf][(wm*32 + 16 + r15)*64 + ko];
      bf16x8 bfr[5];
      #pragma unroll
      for (int fn = 0; fn < 5; ++fn)
        bfr[fn] = *(const bf16x8*)&Bs[buf][(wn*80 + fn*16 + r15)*64 + ko];
      #pragma unroll
      for (int fn = 0; fn < 5; ++fn) {
        acc[0][fn] = __builtin_amdgcn_mfma_f32_16x16x32_bf16(a0, bfr[fn], acc[0][fn], 0,0,0);
        acc[1][fn] = __builtin_amdgcn_mfma_f32_16x16x32_bf16(a1, bfr[fn], acc[1][fn], 0,0,0);
      }
    }
  };

  stage(0, 0);
  __syncthreads();
  for (int kc = 0; kc < NKC; ++kc) {
    if (kc + 1 < NKC) stage((kc+1)&1, kc+1);
    compute(kc&1);
    __syncthreads();
  }

  // epilogue
  const int oc = (lane>>4)*4, pc = lane&15;
  #pragma unroll
  for (int fm = 0; fm < 2; ++fm) {
    const int o = m0 + wm*32 + fm*16 + oc;
    const float4 bv = *(const float4*)&bias[o];
    #pragma unroll
    for (int fn = 0; fn < 5; ++fn) {
      const int p = p0 + wn*80 + fn*16 + pc;
      f32x4 v = acc[fm][fn];
      float r0 = v[0]+bv.x, r1 = v[1]+bv.y, r2 = v[2]+bv.z, r3 = v[3]+bv.w;
      if constexpr (EPI == 0) {
        int row = (p/VV)*32 + (p%VV);
        ushort4 st; st.x=f2bf(r0); st.y=f2bf(r1); st.z=f2bf(r2); st.w=f2bf(r3);
        *(ushort4*)((u16*)outv + ((size_t)n*1024 + row)*384 + o) = st;
      } else if constexpr (EPI == 1) {
        ushort4 st;
        st.x=f2bf(lrelu(r0)); st.y=f2bf(lrelu(r1)); st.z=f2bf(lrelu(r2)); st.w=f2bf(lrelu(r3));
        *(ushort4*)((u16*)outv + ((size_t)n*PIX + p)*256 + o) = st;
      } else if constexpr (EPI == 2) {
        u16* op = (u16*)outv + ((size_t)n*256 + o)*PIX + p;
        op[0]      = f2bf(lrelu(r0));
        op[PIX]    = f2bf(lrelu(r1));
        op[2*PIX]  = f2bf(lrelu(r2));
        op[3*PIX]  = f2bf(lrelu(r3));
      } else {
        const u16* yp = y4b + ((size_t)n*256 + o)*PIX + p;
        float* op = (float*)outv + ((size_t)n*256 + o)*PIX + p;
        op[0]      = lrelu(r0 + bf2f(yp[0]));
        op[PIX]    = lrelu(r1 + bf2f(yp[PIX]));
        op[2*PIX]  = lrelu(r2 + bf2f(yp[2*PIX]));
        op[3*PIX]  = lrelu(r3 + bf2f(yp[3*PIX]));
      }
    }
  }
}

extern "C" void kernel_launch(void* const* d_in, const int* in_sizes, int n_in,
                              void* d_out, int out_size, void* d_ws, size_t ws_size,
                              hipStream_t stream)
{
  const float* x      = (const float*)d_in[0];
  const float* in_w   = (const float*)d_in[1];
  const float* in_b   = (const float*)d_in[2];
  const float* alphas = (const float*)d_in[3];
  const float* att0   = (const float*)d_in[4];
  const float* out_w  = (const float*)d_in[5];
  const float* out_b  = (const float*)d_in[6];
  const float* d1_w   = (const float*)d_in[7];
  const float* d1_b   = (const float*)d_in[8];
  const float* d2_w   = (const float*)d_in[9];
  const float* d2_b   = (const float*)d_in[10];
  const float* ff_w   = (const float*)d_in[11];
  const float* ff_b   = (const float*)d_in[12];
  const float* out_g  = (const float*)d_in[13];
  const float* out_be = (const float*)d_in[14];
  const float* out_m  = (const float*)d_in[15];
  const float* out_v  = (const float*)d_in[16];
  const float* d1_g   = (const float*)d_in[17];
  const float* d1_be  = (const float*)d_in[18];
  const float* d1_m   = (const float*)d_in[19];
  const float* d1_v   = (const float*)d_in[20];
  const float* d2_g   = (const float*)d_in[21];
  const float* d2_be  = (const float*)d_in[22];
  const float* d2_m   = (const float*)d_in[23];
  const float* d2_v   = (const float*)d_in[24];
  const float* ff_g   = (const float*)d_in[25];
  const float* ff_be  = (const float*)d_in[26];
  const float* ff_m   = (const float*)d_in[27];
  const float* ff_v   = (const float*)d_in[28];

  char* ws = (char*)d_ws;
  float* pe  = (float*)(ws + OFF_PE);
  u16*  w1b  = (u16*)(ws + OFF_W1);
  u16*  wk2  = (u16*)(ws + OFF_WK2);
  u16*  wff  = (u16*)(ws + OFF_WFF);
  u16*  wd2  = (u16*)(ws + OFF_WD2);
  float* b1  = (float*)(ws + OFF_B1);
  float* bk2 = (float*)(ws + OFF_BK2);
  float* bff = (float*)(ws + OFF_BFF);
  float* bd2 = (float*)(ws + OFF_BD2);
  u16*  attb = (u16*)(ws + OFF_ATT);
  u16*  xb   = (u16*)(ws + OFF_XB);
  u16*  qkb  = (u16*)(ws + OFF_BIG);   // [128][1024][384]
  u16*  Pb   = (u16*)(ws + OFF_BIG);   // [128][800][768]  (after att done)
  u16*  y4b  = (u16*)(ws + OFF_BIG);   // [128][256][800]  (after G_k2 done)
  u16*  yb   = (u16*)(ws + OFF_Y3);    // [128][800][256]
  u16*  y3b  = (u16*)(ws + OFF_Y3);    // same region, after G_in done

  prep_k<<<256, 256, 0, stream>>>(
      in_w, in_b, out_w, out_b, d1_w, d1_b, d2_w, d2_b, ff_w, ff_b,
      out_g, out_be, out_m, out_v, d1_g, d1_be, d1_m, d1_v,
      d2_g, d2_be, d2_m, d2_v, ff_g, ff_be, ff_m, ff_v,
      pe, w1b, b1, wk2, bk2, wff, bff, wd2, bd2, qkb);

  k0_pe_cvt<<<dim3(TT, NB), 256, 0, stream>>>(x, pe, yb, xb);

  // qk = in_w @ (x+pe) + in_b   -> qkb (padded pixel-major)
  gemm_k<256, 4, 256, 256, 0><<<dim3(5, 3, NB), 512, 0, stream>>>(w1b, b1, yb, yb, qkb, nullptr);

  att_k<<<dim3(SSS, NB), 64, 0, stream>>>(qkb, alphas, att0, attb);

  p_k2<<<dim3(TT, NB), 256, 0, stream>>>(x, attb, Pb);

  // y3 = lrelu( bn(out_w @ P) + bn(d1_w @ x) )   (K=1024 fused)
  gemm_k<1024, 12, 768, 256, 1><<<dim3(5, 2, NB), 512, 0, stream>>>(wk2, bk2, Pb, xb, y3b, nullptr);

  // y4 = lrelu( bn(ff_w @ y3) )
  gemm_k<256, 4, 256, 256, 2><<<dim3(5, 2, NB), 512, 0, stream>>>(wff, bff, y3b, y3b, y4b, nullptr);

  // out = lrelu( bn(d2_w @ x) + y4 )
  gemm_k<256, 4, 256, 256, 3><<<dim3(5, 2, NB), 512, 0, stream>>>(wd2, bd2, xb, xb, d_out, y4b);
}

// Round 7
// 613.580 us; speedup vs baseline: 1.1758x; 1.0431x over previous
//
#include <hip/hip_runtime.h>

typedef unsigned short u16;
typedef __bf16 bf16x8 __attribute__((ext_vector_type(8)));
typedef float f32x4 __attribute__((ext_vector_type(4)));

constexpr int NB = 128;   // batch
constexpr int CC = 256;   // channels
constexpr int TT = 32;
constexpr int VV = 25;
constexpr int SSS = 3;
constexpr int PIX = 800;  // T*V
constexpr float EPSV = 1e-5f;

// ---------------- workspace layout (bytes) ----------------
constexpr size_t OFF_PE  = 0;                        // 6400 f32
constexpr size_t OFF_W1  = 64*1024;                  // 384x256 bf16
constexpr size_t OFF_WK2 = OFF_W1  + 256*1024;       // 256x1024 bf16
constexpr size_t OFF_WFF = OFF_WK2 + 512*1024;       // 256x256 bf16
constexpr size_t OFF_WD2 = OFF_WFF + 128*1024;       // 256x256 bf16
constexpr size_t OFF_B1  = OFF_WD2 + 128*1024;       // b1v [25][384] f32 = 38400 B (reserve 48K)
constexpr size_t OFF_BK2 = OFF_B1  + 48*1024;        // 256 f32
constexpr size_t OFF_BFF = OFF_BK2 + 4096;
constexpr size_t OFF_BD2 = OFF_BFF + 4096;
constexpr size_t OFF_ATT = 2ull*1024*1024;           // attb [128][3][32][32] bf16 = 786,432 B
constexpr size_t OFF_XB  = 4ull*1024*1024;           // xb [128][800][256] bf16 = 52,428,800
constexpr size_t OFF_BIG = OFF_XB + 52428800ull;     // region: qkb [128][1024][384] (100.7MB) -> Pb [128][800][768] (157.3MB) -> y4b (52.4MB)
constexpr size_t OFF_Y3  = OFF_BIG + 157286400ull;   // y3b [128][800][256] bf16

__device__ __forceinline__ float bf2f(u16 h) {
  union { unsigned u; float f; } c; c.u = ((unsigned)h) << 16; return c.f;
}
__device__ __forceinline__ u16 f2bf(float f) {
  union { float f; unsigned u; } c; c.f = f;
  unsigned r = c.u + 0x7fffu + ((c.u >> 16) & 1u);
  return (u16)(r >> 16);
}
__device__ __forceinline__ float lrelu(float z) { return z >= 0.f ? z : 0.1f*z; }

// ---------------- prep: fold BN into bf16 weights, PE table, pad-zero qkb ----------------
__global__ void prep_k(
    const float* __restrict__ in_w,  const float* __restrict__ in_b,
    const float* __restrict__ out_w, const float* __restrict__ out_b,
    const float* __restrict__ d1_w,  const float* __restrict__ d1_b,
    const float* __restrict__ d2_w,  const float* __restrict__ d2_b,
    const float* __restrict__ ff_w,  const float* __restrict__ ff_b,
    const float* __restrict__ out_g, const float* __restrict__ out_be, const float* __restrict__ out_m, const float* __restrict__ out_v,
    const float* __restrict__ d1_g,  const float* __restrict__ d1_be,  const float* __restrict__ d1_m,  const float* __restrict__ d1_v,
    const float* __restrict__ d2_g,  const float* __restrict__ d2_be,  const float* __restrict__ d2_m,  const float* __restrict__ d2_v,
    const float* __restrict__ ff_g,  const float* __restrict__ ff_be,  const float* __restrict__ ff_m,  const float* __restrict__ ff_v,
    float* __restrict__ pe, u16* __restrict__ w1b,
    u16* __restrict__ wk2, float* __restrict__ bk2,
    u16* __restrict__ wff, float* __restrict__ bff,
    u16* __restrict__ wd2, float* __restrict__ bd2,
    u16* __restrict__ qkb)
{
  const int id  = blockIdx.x*blockDim.x + threadIdx.x;
  const int nth = gridDim.x*blockDim.x;
  // PE table: pe[ch][v]; ch=2j -> sin(v*div[j]), ch=2j+1 -> cos
  for (int i = id; i < CC*VV; i += nth) {
    int ch = i / VV, vv = i - ch*VV;
    int j = ch >> 1;
    float ang = (float)vv * expf((float)j * (-2.0f*logf(10000.0f)/(float)CC));
    pe[i] = (ch & 1) ? cosf(ang) : sinf(ang);
  }
  for (int i = id; i < 384*CC; i += nth) w1b[i] = f2bf(in_w[i]);
  // fused out-conv (k<768) + d1-conv (k>=768), both with BN folded
  for (int i = id; i < CC*1024; i += nth) {
    int o = i >> 10, k = i & 1023;
    float w;
    if (k < 768) { float inv = out_g[o]*rsqrtf(out_v[o]+EPSV); w = out_w[o*768+k]*inv; }
    else         { float inv = d1_g[o]*rsqrtf(d1_v[o]+EPSV);   w = d1_w[o*256+(k-768)]*inv; }
    wk2[i] = f2bf(w);
  }
  for (int i = id; i < CC*CC; i += nth) {
    int o = i >> 8;
    wff[i] = f2bf(ff_w[i]*(ff_g[o]*rsqrtf(ff_v[o]+EPSV)));
    wd2[i] = f2bf(d2_w[i]*(d2_g[o]*rsqrtf(d2_v[o]+EPSV)));
  }
  for (int i = id; i < CC; i += nth) {
    float invo = out_g[i]*rsqrtf(out_v[i]+EPSV);
    float invd = d1_g[i]*rsqrtf(d1_v[i]+EPSV);
    bk2[i] = out_b[i]*invo + out_be[i] - out_m[i]*invo
           + d1_b[i]*invd  + d1_be[i]  - d1_m[i]*invd;
    float invf = ff_g[i]*rsqrtf(ff_v[i]+EPSV);
    bff[i] = ff_b[i]*invf + ff_be[i] - ff_m[i]*invf;
    float inv2 = d2_g[i]*rsqrtf(d2_v[i]+EPSV);
    bd2[i] = d2_b[i]*inv2 + d2_be[i] - d2_m[i]*inv2;
  }
  // zero the pad rows (v=25..31) of qkb [n][t*32+v][384]
  for (int i = id; i < NB*TT*7*384; i += nth) {
    int ch = i % 384; int r = i / 384;
    int pr = r % 7; int t = (r/7) % TT; int n = r / (7*TT);
    qkb[((size_t)n*1024 + (size_t)t*32 + 25 + pr)*384 + ch] = 0;
  }
}

// ---------------- prep2: b1v[v][o] = in_b[o] + sum_c in_w[o][c]*pe[c][v] ----------------
__global__ __launch_bounds__(256) void prep2_k(
    const float* __restrict__ in_w, const float* __restrict__ in_b,
    const float* __restrict__ pe, float* __restrict__ b1v)
{
  const int i = blockIdx.x*blockDim.x + threadIdx.x;
  if (i >= 384*VV) return;
  const int o = i % 384, v = i / 384;
  float acc = in_b[o];
  for (int c = 0; c < CC; ++c) acc += in_w[o*CC+c]*pe[c*VV+v];
  b1v[v*384+o] = acc;
}

// ---------------- k0: xb[n][p][c] = bf16(x) (pixel-major transpose) ----------------
__global__ __launch_bounds__(256) void k0_cvt(
    const float* __restrict__ x, u16* __restrict__ xb)
{
  __shared__ float xt[CC*VV];
  const int t = blockIdx.x, n = blockIdx.y;
  const float* xs = x + (size_t)n*CC*PIX + t*VV;
  for (int f = threadIdx.x; f < CC*VV; f += 256) {
    int c = f / VV, u = f - c*VV;
    xt[f] = xs[(size_t)c*PIX + u];
  }
  __syncthreads();
  const int c = threadIdx.x;
  u16* xrow = xb + ((size_t)n*PIX + t*VV)*CC + c;
  #pragma unroll
  for (int u = 0; u < VV; ++u)
    xrow[(size_t)u*CC] = f2bf(xt[c*VV+u]);
}

// ---------------- att: per (n,s) 1-wave MFMA Q^T K, tanh epilogue -> attb[v][u] bf16 ----------------
// attb [n][s][v:32][u:32] = att^T, zero-padded (B-operand-ready, k(=u)-contiguous)
__global__ __launch_bounds__(64) void att_k(
    const u16* __restrict__ qkb, const float* __restrict__ alphas,
    const float* __restrict__ att0, u16* __restrict__ attb)
{
  const int s = blockIdx.x, n = blockIdx.y, lane = threadIdx.x;
  const u16* qb = qkb + (size_t)n*1024*384 + s*64;
  const u16* kb = qb + 192;   // k channels start at 3*64
  f32x4 acc[2][2];
  #pragma unroll
  for (int i = 0; i < 2; ++i)
    #pragma unroll
    for (int j = 0; j < 2; ++j) acc[i][j] = f32x4{0.f,0.f,0.f,0.f};

  for (int t = 0; t < TT; ++t) {
    const u16* qrow = qb + (size_t)t*32*384;
    const u16* krow = kb + (size_t)t*32*384;
    #pragma unroll
    for (int ks = 0; ks < 2; ++ks) {
      const int ko = ks*32 + (lane>>4)*8;
      bf16x8 a0 = *(const bf16x8*)(qrow + (size_t)(lane&15)*384 + ko);
      bf16x8 a1 = *(const bf16x8*)(qrow + (size_t)(16+(lane&15))*384 + ko);
      bf16x8 b0 = *(const bf16x8*)(krow + (size_t)(lane&15)*384 + ko);
      bf16x8 b1 = *(const bf16x8*)(krow + (size_t)(16+(lane&15))*384 + ko);
      acc[0][0] = __builtin_amdgcn_mfma_f32_16x16x32_bf16(a0, b0, acc[0][0], 0,0,0);
      acc[0][1] = __builtin_amdgcn_mfma_f32_16x16x32_bf16(a0, b1, acc[0][1], 0,0,0);
      acc[1][0] = __builtin_amdgcn_mfma_f32_16x16x32_bf16(a1, b0, acc[1][0], 0,0,0);
      acc[1][1] = __builtin_amdgcn_mfma_f32_16x16x32_bf16(a1, b1, acc[1][1], 0,0,0);
    }
  }
  const float alpha = alphas[s];
  const float sc = 1.0f/2048.0f;
  u16* ab = attb + ((size_t)n*SSS + s)*1024;   // [v:32][u:32]
  #pragma unroll
  for (int fm = 0; fm < 2; ++fm)
    #pragma unroll
    for (int fn = 0; fn < 2; ++fn)
      #pragma unroll
      for (int j = 0; j < 4; ++j) {
        int u = fm*16 + (lane>>4)*4 + j;   // q index (row of att)
        int v = fn*16 + (lane&15);         // k index (col of att)
        float val = 0.f;
        if (u < VV && v < VV)
          val = tanhf(acc[fm][fn][j]*sc)*alpha + att0[s*VV*VV + u*VV + v];
        ab[v*32 + u] = f2bf(val);          // transposed store
      }
}

// ---------------- p_k2: Pb[n][p][s*256+c] = sum_u x[c][u]*att[u][v] via MFMA ----------------
// Reads xb (bf16 pixel-major, coalesced 512B rows) + attb. LDS rows padded to 40 elems.
__global__ __launch_bounds__(256) void p_k2(
    const u16* __restrict__ xb, const u16* __restrict__ attb, u16* __restrict__ Pb)
{
  __shared__ u16 Xs[CC*40];       // [c:256][u:40]  20,480 B
  __shared__ u16 Al[SSS*32*40];   // [s][v:32][u:40] 7,680 B
  const int t = blockIdx.x, n = blockIdx.y;
  const u16* xrow = xb + ((size_t)n*PIX + t*VV)*CC;
  // transpose-stage: read u16 coalesced (lane->c), scatter to [c][u]
  for (int f = threadIdx.x; f < VV*CC; f += 256) {
    int u = f >> 8, c = f & 255;
    Xs[c*40+u] = xrow[(size_t)u*CC + c];
  }
  for (int idx = threadIdx.x; idx < CC*7; idx += 256) {
    int c = idx / 7, u = 25 + idx % 7;
    Xs[c*40+u] = 0;               // zero K-pad u=25..31
  }
  const u16* ab = attb + (size_t)n*SSS*1024;
  for (int f = threadIdx.x; f < SSS*1024; f += 256) {
    int sv = f >> 5, u = f & 31;
    Al[sv*40+u] = ab[f];
  }
  __syncthreads();

  const int lane = threadIdx.x & 63, w = threadIdx.x >> 6;
  const int cb0 = w*64;                 // wave's 64-channel slab
  const int k0 = (lane>>4)*8;
  const int r15 = lane & 15;
  f32x4 acc[SSS][4][2];
  #pragma unroll
  for (int s = 0; s < SSS; ++s)
    #pragma unroll
    for (int mt = 0; mt < 4; ++mt)
      #pragma unroll
      for (int nt = 0; nt < 2; ++nt) acc[s][mt][nt] = f32x4{0.f,0.f,0.f,0.f};

  #pragma unroll
  for (int s = 0; s < SSS; ++s) {
    bf16x8 b0 = *(const bf16x8*)&Al[((s*32) + r15)*40 + k0];
    bf16x8 b1 = *(const bf16x8*)&Al[((s*32) + 16 + r15)*40 + k0];
    #pragma unroll
    for (int mt = 0; mt < 4; ++mt) {
      bf16x8 a = *(const bf16x8*)&Xs[(cb0 + mt*16 + r15)*40 + k0];
      acc[s][mt][0] = __builtin_amdgcn_mfma_f32_16x16x32_bf16(a, b0, acc[s][mt][0], 0,0,0);
      acc[s][mt][1] = __builtin_amdgcn_mfma_f32_16x16x32_bf16(a, b1, acc[s][mt][1], 0,0,0);
    }
  }

  const int j4 = (lane>>4)*4;
  #pragma unroll
  for (int s = 0; s < SSS; ++s)
    #pragma unroll
    for (int nt = 0; nt < 2; ++nt) {
      const int v = nt*16 + r15;
      if (v < VV) {
        u16* dst0 = Pb + ((size_t)n*PIX + t*VV + v)*768 + s*CC + cb0 + j4;
        #pragma unroll
        for (int mt = 0; mt < 4; ++mt) {
          f32x4 a = acc[s][mt][nt];
          ushort4 st; st.x=f2bf(a[0]); st.y=f2bf(a[1]); st.z=f2bf(a[2]); st.w=f2bf(a[3]);
          *(ushort4*)(dst0 + mt*16) = st;
        }
      }
    }
}

// ---------------- GEMM: OUT[o, p] = W[o,:] . Bpm[p,:] + bias, per-n ----------------
// m97-style 2-barrier dbuf + T2 XOR-swizzle (rule #21: linear LDS dest for
// global_load_lds, INVERSE-swizzled global source, swizzled ds_read).
// EPI: 0 = +b1v[p%25][o], store bf16 to qkb [n][(p/25)*32+p%25][384]
//      1 = lrelu, store bf16 pixel-major [n][p][256]
//      2 = lrelu, store bf16 chan-major [n][256][800]
//      3 = +y4b, lrelu, store f32 chan-major [n][256][800]
template<int KTOT, int NKC0, int BS0, int BS1, int EPI>
__global__ __launch_bounds__(512, 1)
void gemm_k(const u16* __restrict__ W, const float* __restrict__ bias,
            const u16* __restrict__ B0, const u16* __restrict__ B1,
            void* __restrict__ outv, const u16* __restrict__ y4b)
{
  constexpr int NKC = KTOT/64;
  __shared__ u16 As[2][128*64];
  __shared__ u16 Bs[2][160*64];
  const int tid = threadIdx.x;
  const int lane = tid & 63, wid = tid >> 6;
  const int wm = wid >> 1, wn = wid & 1;
  const int pt = blockIdx.x, mt = blockIdx.y, n = blockIdx.z;
  const int m0 = mt*128, p0 = pt*160;
  const int lr = lane >> 3;                      // 0..7 (== row&7 of this lane's dest row)
  const int lc = (((lane & 7) ^ lr)) * 8;        // inverse-swizzled source slot

  f32x4 acc[2][5];
  #pragma unroll
  for (int i = 0; i < 2; ++i)
    #pragma unroll
    for (int j = 0; j < 5; ++j) acc[i][j] = f32x4{0.f,0.f,0.f,0.f};

  auto stage = [&](int buf, int kc) {
    const u16* wsrc = W + (size_t)m0*KTOT + (size_t)kc*64;
    for (int g = wid; g < 16; g += 8) {
      const u16* src = wsrc + (size_t)(g*8 + lr)*KTOT + lc;
      __builtin_amdgcn_global_load_lds(
          (const __attribute__((address_space(1))) void*)src,
          (__attribute__((address_space(3))) void*)(&As[buf][g*512]), 16, 0, 0);
    }
    const u16* bbase; int bs;
    if (NKC0 >= NKC || kc < NKC0) {
      bbase = B0 + ((size_t)n*PIX + p0)*BS0 + (size_t)kc*64; bs = BS0;
    } else {
      bbase = B1 + ((size_t)n*PIX + p0)*BS1 + (size_t)(kc-NKC0)*64; bs = BS1;
    }
    for (int g = wid; g < 20; g += 8) {
      const u16* src = bbase + (size_t)(g*8 + lr)*bs + lc;
      __builtin_amdgcn_global_load_lds(
          (const __attribute__((address_space(1))) void*)src,
          (__attribute__((address_space(3))) void*)(&Bs[buf][g*512]), 16, 0, 0);
    }
  };

  auto compute = [&](int buf) {
    const int par = lane & 7;
    const int gq  = lane >> 4;
    const int r15 = lane & 15;
    #pragma unroll
    for (int ks = 0; ks < 2; ++ks) {
      const int ko = (((ks*4 + gq) ^ par)) * 8;  // swizzled 16B-slot read
      bf16x8 a0 = *(const bf16x8*)&As[buf][(wm*32 + r15)*64 + ko];
      bf16x8 a1 = *(const bf16x8*)&As[buf][(wm*32 + 16 + r15)*64 + ko];
      bf16x8 bfr[5];
      #pragma unroll
      for (int fn = 0; fn < 5; ++fn)
        bfr[fn] = *(const bf16x8*)&Bs[buf][(wn*80 + fn*16 + r15)*64 + ko];
      #pragma unroll
      for (int fn = 0; fn < 5; ++fn) {
        acc[0][fn] = __builtin_amdgcn_mfma_f32_16x16x32_bf16(a0, bfr[fn], acc[0][fn], 0,0,0);
        acc[1][fn] = __builtin_amdgcn_mfma_f32_16x16x32_bf16(a1, bfr[fn], acc[1][fn], 0,0,0);
      }
    }
  };

  stage(0, 0);
  __syncthreads();
  for (int kc = 0; kc < NKC; ++kc) {
    if (kc + 1 < NKC) stage((kc+1)&1, kc+1);
    compute(kc&1);
    __syncthreads();
  }

  // epilogue
  const int oc = (lane>>4)*4, pc = lane&15;
  #pragma unroll
  for (int fm = 0; fm < 2; ++fm) {
    const int o = m0 + wm*32 + fm*16 + oc;
    #pragma unroll
    for (int fn = 0; fn < 5; ++fn) {
      const int p = p0 + wn*80 + fn*16 + pc;
      f32x4 v = acc[fm][fn];
      float4 bv;
      if constexpr (EPI == 0) bv = *(const float4*)&bias[(p % VV)*384 + o];
      else                    bv = *(const float4*)&bias[o];
      float r0 = v[0]+bv.x, r1 = v[1]+bv.y, r2 = v[2]+bv.z, r3 = v[3]+bv.w;
      if constexpr (EPI == 0) {
        int row = (p/VV)*32 + (p%VV);
        ushort4 st; st.x=f2bf(r0); st.y=f2bf(r1); st.z=f2bf(r2); st.w=f2bf(r3);
        *(ushort4*)((u16*)outv + ((size_t)n*1024 + row)*384 + o) = st;
      } else if constexpr (EPI == 1) {
        ushort4 st;
        st.x=f2bf(lrelu(r0)); st.y=f2bf(lrelu(r1)); st.z=f2bf(lrelu(r2)); st.w=f2bf(lrelu(r3));
        *(ushort4*)((u16*)outv + ((size_t)n*PIX + p)*256 + o) = st;
      } else if constexpr (EPI == 2) {
        u16* op = (u16*)outv + ((size_t)n*256 + o)*PIX + p;
        op[0]      = f2bf(lrelu(r0));
        op[PIX]    = f2bf(lrelu(r1));
        op[2*PIX]  = f2bf(lrelu(r2));
        op[3*PIX]  = f2bf(lrelu(r3));
      } else {
        const u16* yp = y4b + ((size_t)n*256 + o)*PIX + p;
        float* op = (float*)outv + ((size_t)n*256 + o)*PIX + p;
        op[0]      = lrelu(r0 + bf2f(yp[0]));
        op[PIX]    = lrelu(r1 + bf2f(yp[PIX]));
        op[2*PIX]  = lrelu(r2 + bf2f(yp[2*PIX]));
        op[3*PIX]  = lrelu(r3 + bf2f(yp[3*PIX]));
      }
    }
  }
}

extern "C" void kernel_launch(void* const* d_in, const int* in_sizes, int n_in,
                              void* d_out, int out_size, void* d_ws, size_t ws_size,
                              hipStream_t stream)
{
  const float* x      = (const float*)d_in[0];
  const float* in_w   = (const float*)d_in[1];
  const float* in_b   = (const float*)d_in[2];
  const float* alphas = (const float*)d_in[3];
  const float* att0   = (const float*)d_in[4];
  const float* out_w  = (const float*)d_in[5];
  const float* out_b  = (const float*)d_in[6];
  const float* d1_w   = (const float*)d_in[7];
  const float* d1_b   = (const float*)d_in[8];
  const float* d2_w   = (const float*)d_in[9];
  const float* d2_b   = (const float*)d_in[10];
  const float* ff_w   = (const float*)d_in[11];
  const float* ff_b   = (const float*)d_in[12];
  const float* out_g  = (const float*)d_in[13];
  const float* out_be = (const float*)d_in[14];
  const float* out_m  = (const float*)d_in[15];
  const float* out_v  = (const float*)d_in[16];
  const float* d1_g   = (const float*)d_in[17];
  const float* d1_be  = (const float*)d_in[18];
  const float* d1_m   = (const float*)d_in[19];
  const float* d1_v   = (const float*)d_in[20];
  const float* d2_g   = (const float*)d_in[21];
  const float* d2_be  = (const float*)d_in[22];
  const float* d2_m   = (const float*)d_in[23];
  const float* d2_v   = (const float*)d_in[24];
  const float* ff_g   = (const float*)d_in[25];
  const float* ff_be  = (const float*)d_in[26];
  const float* ff_m   = (const float*)d_in[27];
  const float* ff_v   = (const float*)d_in[28];

  char* ws = (char*)d_ws;
  float* pe  = (float*)(ws + OFF_PE);
  u16*  w1b  = (u16*)(ws + OFF_W1);
  u16*  wk2  = (u16*)(ws + OFF_WK2);
  u16*  wff  = (u16*)(ws + OFF_WFF);
  u16*  wd2  = (u16*)(ws + OFF_WD2);
  float* b1v = (float*)(ws + OFF_B1);
  float* bk2 = (float*)(ws + OFF_BK2);
  float* bff = (float*)(ws + OFF_BFF);
  float* bd2 = (float*)(ws + OFF_BD2);
  u16*  attb = (u16*)(ws + OFF_ATT);
  u16*  xb   = (u16*)(ws + OFF_XB);
  u16*  qkb  = (u16*)(ws + OFF_BIG);   // [128][1024][384]
  u16*  Pb   = (u16*)(ws + OFF_BIG);   // [128][800][768]  (after att done)
  u16*  y4b  = (u16*)(ws + OFF_BIG);   // [128][256][800]  (after G_k2 done)
  u16*  y3b  = (u16*)(ws + OFF_Y3);    // [128][800][256]

  prep_k<<<256, 256, 0, stream>>>(
      in_w, in_b, out_w, out_b, d1_w, d1_b, d2_w, d2_b, ff_w, ff_b,
      out_g, out_be, out_m, out_v, d1_g, d1_be, d1_m, d1_v,
      d2_g, d2_be, d2_m, d2_v, ff_g, ff_be, ff_m, ff_v,
      pe, w1b, wk2, bk2, wff, bff, wd2, bd2, qkb);

  prep2_k<<<(384*VV + 255)/256, 256, 0, stream>>>(in_w, in_b, pe, b1v);

  k0_cvt<<<dim3(TT, NB), 256, 0, stream>>>(x, xb);

  // qk = in_w @ x + b1v(o,v)   -> qkb (padded pixel-major)
  gemm_k<256, 4, 256, 256, 0><<<dim3(5, 3, NB), 512, 0, stream>>>(w1b, b1v, xb, xb, qkb, nullptr);

  att_k<<<dim3(SSS, NB), 64, 0, stream>>>(qkb, alphas, att0, attb);

  p_k2<<<dim3(TT, NB), 256, 0, stream>>>(xb, attb, Pb);

  // y3 = lrelu( bn(out_w @ P) + bn(d1_w @ x) )   (K=1024 fused)
  gemm_k<1024, 12, 768, 256, 1><<<dim3(5, 2, NB), 512, 0, stream>>>(wk2, bk2, Pb, xb, y3b, nullptr);

  // y4 = lrelu( bn(ff_w @ y3) )
  gemm_k<256, 4, 256, 256, 2><<<dim3(5, 2, NB), 512, 0, stream>>>(wff, bff, y3b, y3b, y4b, nullptr);

  // out = lrelu( bn(d2_w @ x) + y4 )
  gemm_k<256, 4, 256, 256, 3><<<dim3(5, 2, NB), 512, 0, stream>>>(wd2, bd2, xb, xb, d_out, y4b);
}

// Round 8
// 576.570 us; speedup vs baseline: 1.2512x; 1.0642x over previous
//
#include <hip/hip_runtime.h>

typedef unsigned short u16;
typedef __bf16 bf16x8 __attribute__((ext_vector_type(8)));
typedef float f32x4 __attribute__((ext_vector_type(4)));

constexpr int NB = 128;   // batch
constexpr int CC = 256;   // channels
constexpr int TT = 32;
constexpr int VV = 25;
constexpr int SSS = 3;
constexpr int PIX = 800;  // T*V
constexpr float EPSV = 1e-5f;

// ---------------- workspace layout (bytes) ----------------
constexpr size_t OFF_PE  = 0;                        // 6400 f32
constexpr size_t OFF_W1  = 64*1024;                  // 384x256 bf16
constexpr size_t OFF_WK2 = OFF_W1  + 256*1024;       // 256x1024 bf16
constexpr size_t OFF_WFF = OFF_WK2 + 512*1024;       // 256x256 bf16
constexpr size_t OFF_WD2 = OFF_WFF + 128*1024;       // 256x256 bf16
constexpr size_t OFF_B1  = OFF_WD2 + 128*1024;       // b1v [25][384] f32 = 38400 B (reserve 48K)
constexpr size_t OFF_BK2 = OFF_B1  + 48*1024;        // 256 f32
constexpr size_t OFF_BFF = OFF_BK2 + 4096;
constexpr size_t OFF_BD2 = OFF_BFF + 4096;
constexpr size_t OFF_ATT = 2ull*1024*1024;           // attb [128][3][32][32] bf16 = 786,432 B
constexpr size_t OFF_XB  = 4ull*1024*1024;           // xb [128][800][256] bf16 = 52,428,800
constexpr size_t OFF_BIG = OFF_XB + 52428800ull;     // region: qkb [128][1024][384] (100.7MB) -> Pb [128][800][768] (157.3MB)
constexpr size_t OFF_Y3  = OFF_BIG + 157286400ull;   // y3b [128][800][256] bf16

__device__ __forceinline__ float bf2f(u16 h) {
  union { unsigned u; float f; } c; c.u = ((unsigned)h) << 16; return c.f;
}
__device__ __forceinline__ u16 f2bf(float f) {
  union { float f; unsigned u; } c; c.f = f;
  unsigned r = c.u + 0x7fffu + ((c.u >> 16) & 1u);
  return (u16)(r >> 16);
}
__device__ __forceinline__ float lrelu(float z) { return z >= 0.f ? z : 0.1f*z; }

// ---------------- prep: fold BN into bf16 weights, PE table, pad-zero qkb ----------------
__global__ void prep_k(
    const float* __restrict__ in_w,  const float* __restrict__ in_b,
    const float* __restrict__ out_w, const float* __restrict__ out_b,
    const float* __restrict__ d1_w,  const float* __restrict__ d1_b,
    const float* __restrict__ d2_w,  const float* __restrict__ d2_b,
    const float* __restrict__ ff_w,  const float* __restrict__ ff_b,
    const float* __restrict__ out_g, const float* __restrict__ out_be, const float* __restrict__ out_m, const float* __restrict__ out_v,
    const float* __restrict__ d1_g,  const float* __restrict__ d1_be,  const float* __restrict__ d1_m,  const float* __restrict__ d1_v,
    const float* __restrict__ d2_g,  const float* __restrict__ d2_be,  const float* __restrict__ d2_m,  const float* __restrict__ d2_v,
    const float* __restrict__ ff_g,  const float* __restrict__ ff_be,  const float* __restrict__ ff_m,  const float* __restrict__ ff_v,
    float* __restrict__ pe, u16* __restrict__ w1b,
    u16* __restrict__ wk2, float* __restrict__ bk2,
    u16* __restrict__ wff, float* __restrict__ bff,
    u16* __restrict__ wd2, float* __restrict__ bd2,
    u16* __restrict__ qkb)
{
  const int id  = blockIdx.x*blockDim.x + threadIdx.x;
  const int nth = gridDim.x*blockDim.x;
  // PE table: pe[ch][v]; ch=2j -> sin(v*div[j]), ch=2j+1 -> cos
  for (int i = id; i < CC*VV; i += nth) {
    int ch = i / VV, vv = i - ch*VV;
    int j = ch >> 1;
    float ang = (float)vv * expf((float)j * (-2.0f*logf(10000.0f)/(float)CC));
    pe[i] = (ch & 1) ? cosf(ang) : sinf(ang);
  }
  for (int i = id; i < 384*CC; i += nth) w1b[i] = f2bf(in_w[i]);
  // fused out-conv (k<768) + d1-conv (k>=768), both with BN folded
  for (int i = id; i < CC*1024; i += nth) {
    int o = i >> 10, k = i & 1023;
    float w;
    if (k < 768) { float inv = out_g[o]*rsqrtf(out_v[o]+EPSV); w = out_w[o*768+k]*inv; }
    else         { float inv = d1_g[o]*rsqrtf(d1_v[o]+EPSV);   w = d1_w[o*256+(k-768)]*inv; }
    wk2[i] = f2bf(w);
  }
  for (int i = id; i < CC*CC; i += nth) {
    int o = i >> 8;
    wff[i] = f2bf(ff_w[i]*(ff_g[o]*rsqrtf(ff_v[o]+EPSV)));
    wd2[i] = f2bf(d2_w[i]*(d2_g[o]*rsqrtf(d2_v[o]+EPSV)));
  }
  for (int i = id; i < CC; i += nth) {
    float invo = out_g[i]*rsqrtf(out_v[i]+EPSV);
    float invd = d1_g[i]*rsqrtf(d1_v[i]+EPSV);
    bk2[i] = out_b[i]*invo + out_be[i] - out_m[i]*invo
           + d1_b[i]*invd  + d1_be[i]  - d1_m[i]*invd;
    float invf = ff_g[i]*rsqrtf(ff_v[i]+EPSV);
    bff[i] = ff_b[i]*invf + ff_be[i] - ff_m[i]*invf;
    float inv2 = d2_g[i]*rsqrtf(d2_v[i]+EPSV);
    bd2[i] = d2_b[i]*inv2 + d2_be[i] - d2_m[i]*inv2;
  }
  // zero the pad rows (v=25..31) of qkb [n][t*32+v][384]
  for (int i = id; i < NB*TT*7*384; i += nth) {
    int ch = i % 384; int r = i / 384;
    int pr = r % 7; int t = (r/7) % TT; int n = r / (7*TT);
    qkb[((size_t)n*1024 + (size_t)t*32 + 25 + pr)*384 + ch] = 0;
  }
}

// ---------------- prep2: b1v[v][o] = in_b[o] + sum_c in_w[o][c]*pe[c][v] ----------------
__global__ __launch_bounds__(256) void prep2_k(
    const float* __restrict__ in_w, const float* __restrict__ in_b,
    const float* __restrict__ pe, float* __restrict__ b1v)
{
  const int i = blockIdx.x*blockDim.x + threadIdx.x;
  if (i >= 384*VV) return;
  const int o = i % 384, v = i / 384;
  float acc = in_b[o];
  for (int c = 0; c < CC; ++c) acc += in_w[o*CC+c]*pe[c*VV+v];
  b1v[v*384+o] = acc;
}

// ---------------- k0: xb[n][p][c] = bf16(x) (pixel-major transpose) ----------------
__global__ __launch_bounds__(256) void k0_cvt(
    const float* __restrict__ x, u16* __restrict__ xb)
{
  __shared__ float xt[CC*VV];
  const int t = blockIdx.x, n = blockIdx.y;
  const float* xs = x + (size_t)n*CC*PIX + t*VV;
  for (int f = threadIdx.x; f < CC*VV; f += 256) {
    int c = f / VV, u = f - c*VV;
    xt[f] = xs[(size_t)c*PIX + u];
  }
  __syncthreads();
  const int c = threadIdx.x;
  u16* xrow = xb + ((size_t)n*PIX + t*VV)*CC + c;
  #pragma unroll
  for (int u = 0; u < VV; ++u)
    xrow[(size_t)u*CC] = f2bf(xt[c*VV+u]);
}

// ---------------- att: per (n,s) 4-wave MFMA Q^T K (t-split), LDS reduce, tanh epilogue ----------------
// attb [n][s][v:32][u:32] = att^T, zero-padded (B-operand-ready, k(=u)-contiguous)
__global__ __launch_bounds__(256) void att_k(
    const u16* __restrict__ qkb, const float* __restrict__ alphas,
    const float* __restrict__ att0, u16* __restrict__ attb)
{
  __shared__ float red[3][64][17];   // waves 1..3 partials, lane-padded
  const int s = blockIdx.x, n = blockIdx.y;
  const int lane = threadIdx.x & 63, w = threadIdx.x >> 6;
  const u16* qb = qkb + (size_t)n*1024*384 + s*64;
  const u16* kb = qb + 192;   // k channels start at 3*64
  f32x4 acc[2][2];
  #pragma unroll
  for (int i = 0; i < 2; ++i)
    #pragma unroll
    for (int j = 0; j < 2; ++j) acc[i][j] = f32x4{0.f,0.f,0.f,0.f};

  for (int t = w; t < TT; t += 4) {
    const u16* qrow = qb + (size_t)t*32*384;
    const u16* krow = kb + (size_t)t*32*384;
    #pragma unroll
    for (int ks = 0; ks < 2; ++ks) {
      const int ko = ks*32 + (lane>>4)*8;
      bf16x8 a0 = *(const bf16x8*)(qrow + (size_t)(lane&15)*384 + ko);
      bf16x8 a1 = *(const bf16x8*)(qrow + (size_t)(16+(lane&15))*384 + ko);
      bf16x8 b0 = *(const bf16x8*)(krow + (size_t)(lane&15)*384 + ko);
      bf16x8 b1 = *(const bf16x8*)(krow + (size_t)(16+(lane&15))*384 + ko);
      acc[0][0] = __builtin_amdgcn_mfma_f32_16x16x32_bf16(a0, b0, acc[0][0], 0,0,0);
      acc[0][1] = __builtin_amdgcn_mfma_f32_16x16x32_bf16(a0, b1, acc[0][1], 0,0,0);
      acc[1][0] = __builtin_amdgcn_mfma_f32_16x16x32_bf16(a1, b0, acc[1][0], 0,0,0);
      acc[1][1] = __builtin_amdgcn_mfma_f32_16x16x32_bf16(a1, b1, acc[1][1], 0,0,0);
    }
  }
  if (w > 0) {
    float* dst = &red[w-1][lane][0];
    #pragma unroll
    for (int fm = 0; fm < 2; ++fm)
      #pragma unroll
      for (int fn = 0; fn < 2; ++fn)
        #pragma unroll
        for (int j = 0; j < 4; ++j)
          dst[(fm*2+fn)*4+j] = acc[fm][fn][j];
  }
  __syncthreads();
  if (w == 0) {
    #pragma unroll
    for (int r = 0; r < 3; ++r) {
      const float* src = &red[r][lane][0];
      #pragma unroll
      for (int fm = 0; fm < 2; ++fm)
        #pragma unroll
        for (int fn = 0; fn < 2; ++fn)
          #pragma unroll
          for (int j = 0; j < 4; ++j)
            acc[fm][fn][j] += src[(fm*2+fn)*4+j];
    }
    const float alpha = alphas[s];
    const float sc = 1.0f/2048.0f;
    u16* ab = attb + ((size_t)n*SSS + s)*1024;   // [v:32][u:32]
    #pragma unroll
    for (int fm = 0; fm < 2; ++fm)
      #pragma unroll
      for (int fn = 0; fn < 2; ++fn)
        #pragma unroll
        for (int j = 0; j < 4; ++j) {
          int u = fm*16 + (lane>>4)*4 + j;   // q index (row of att)
          int v = fn*16 + (lane&15);         // k index (col of att)
          float val = 0.f;
          if (u < VV && v < VV)
            val = tanhf(acc[fm][fn][j]*sc)*alpha + att0[s*VV*VV + u*VV + v];
          ab[v*32 + u] = f2bf(val);          // transposed store
        }
  }
}

// ---------------- p_k2: Pb[n][p][s*256+c] = sum_u x[c][u]*att[u][v] via MFMA ----------------
// Reads xb (bf16 pixel-major, coalesced 512B rows) + attb. LDS rows padded to 40 elems.
__global__ __launch_bounds__(256) void p_k2(
    const u16* __restrict__ xb, const u16* __restrict__ attb, u16* __restrict__ Pb)
{
  __shared__ u16 Xs[CC*40];       // [c:256][u:40]  20,480 B
  __shared__ u16 Al[SSS*32*40];   // [s][v:32][u:40] 7,680 B
  const int t = blockIdx.x, n = blockIdx.y;
  const u16* xrow = xb + ((size_t)n*PIX + t*VV)*CC;
  // transpose-stage: read u16 coalesced (lane->c), scatter to [c][u]
  for (int f = threadIdx.x; f < VV*CC; f += 256) {
    int u = f >> 8, c = f & 255;
    Xs[c*40+u] = xrow[(size_t)u*CC + c];
  }
  for (int idx = threadIdx.x; idx < CC*7; idx += 256) {
    int c = idx / 7, u = 25 + idx % 7;
    Xs[c*40+u] = 0;               // zero K-pad u=25..31
  }
  const u16* ab = attb + (size_t)n*SSS*1024;
  for (int f = threadIdx.x; f < SSS*1024; f += 256) {
    int sv = f >> 5, u = f & 31;
    Al[sv*40+u] = ab[f];
  }
  __syncthreads();

  const int lane = threadIdx.x & 63, w = threadIdx.x >> 6;
  const int cb0 = w*64;                 // wave's 64-channel slab
  const int k0 = (lane>>4)*8;
  const int r15 = lane & 15;
  f32x4 acc[SSS][4][2];
  #pragma unroll
  for (int s = 0; s < SSS; ++s)
    #pragma unroll
    for (int mt = 0; mt < 4; ++mt)
      #pragma unroll
      for (int nt = 0; nt < 2; ++nt) acc[s][mt][nt] = f32x4{0.f,0.f,0.f,0.f};

  #pragma unroll
  for (int s = 0; s < SSS; ++s) {
    bf16x8 b0 = *(const bf16x8*)&Al[((s*32) + r15)*40 + k0];
    bf16x8 b1 = *(const bf16x8*)&Al[((s*32) + 16 + r15)*40 + k0];
    #pragma unroll
    for (int mt = 0; mt < 4; ++mt) {
      bf16x8 a = *(const bf16x8*)&Xs[(cb0 + mt*16 + r15)*40 + k0];
      acc[s][mt][0] = __builtin_amdgcn_mfma_f32_16x16x32_bf16(a, b0, acc[s][mt][0], 0,0,0);
      acc[s][mt][1] = __builtin_amdgcn_mfma_f32_16x16x32_bf16(a, b1, acc[s][mt][1], 0,0,0);
    }
  }

  const int j4 = (lane>>4)*4;
  #pragma unroll
  for (int s = 0; s < SSS; ++s)
    #pragma unroll
    for (int nt = 0; nt < 2; ++nt) {
      const int v = nt*16 + r15;
      if (v < VV) {
        u16* dst0 = Pb + ((size_t)n*PIX + t*VV + v)*768 + s*CC + cb0 + j4;
        #pragma unroll
        for (int mt = 0; mt < 4; ++mt) {
          f32x4 a = acc[s][mt][nt];
          ushort4 st; st.x=f2bf(a[0]); st.y=f2bf(a[1]); st.z=f2bf(a[2]); st.w=f2bf(a[3]);
          *(ushort4*)(dst0 + mt*16) = st;
        }
      }
    }
}

// ---------------- GEMM: OUT[o, p] = W[o,:] . Bpm[p,:] + bias, per-n ----------------
// m97-style 2-barrier dbuf + T2 XOR-swizzle (rule #21: linear LDS dest for
// global_load_lds, INVERSE-swizzled global source, swizzled ds_read).
// EPI: 0 = +b1v[p%25][o], store bf16 to qkb [n][(p/25)*32+p%25][384]
//      1 = lrelu, store bf16 pixel-major [n][p][256]
template<int KTOT, int NKC0, int BS0, int BS1, int EPI>
__global__ __launch_bounds__(512, 1)
void gemm_k(const u16* __restrict__ W, const float* __restrict__ bias,
            const u16* __restrict__ B0, const u16* __restrict__ B1,
            void* __restrict__ outv)
{
  constexpr int NKC = KTOT/64;
  __shared__ u16 As[2][128*64];
  __shared__ u16 Bs[2][160*64];
  const int tid = threadIdx.x;
  const int lane = tid & 63, wid = tid >> 6;
  const int wm = wid >> 1, wn = wid & 1;
  const int pt = blockIdx.x, mt = blockIdx.y, n = blockIdx.z;
  const int m0 = mt*128, p0 = pt*160;
  const int lr = lane >> 3;                      // 0..7 (== row&7 of this lane's dest row)
  const int lc = (((lane & 7) ^ lr)) * 8;        // inverse-swizzled source slot

  f32x4 acc[2][5];
  #pragma unroll
  for (int i = 0; i < 2; ++i)
    #pragma unroll
    for (int j = 0; j < 5; ++j) acc[i][j] = f32x4{0.f,0.f,0.f,0.f};

  auto stage = [&](int buf, int kc) {
    const u16* wsrc = W + (size_t)m0*KTOT + (size_t)kc*64;
    for (int g = wid; g < 16; g += 8) {
      const u16* src = wsrc + (size_t)(g*8 + lr)*KTOT + lc;
      __builtin_amdgcn_global_load_lds(
          (const __attribute__((address_space(1))) void*)src,
          (__attribute__((address_space(3))) void*)(&As[buf][g*512]), 16, 0, 0);
    }
    const u16* bbase; int bs;
    if (NKC0 >= NKC || kc < NKC0) {
      bbase = B0 + ((size_t)n*PIX + p0)*BS0 + (size_t)kc*64; bs = BS0;
    } else {
      bbase = B1 + ((size_t)n*PIX + p0)*BS1 + (size_t)(kc-NKC0)*64; bs = BS1;
    }
    for (int g = wid; g < 20; g += 8) {
      const u16* src = bbase + (size_t)(g*8 + lr)*bs + lc;
      __builtin_amdgcn_global_load_lds(
          (const __attribute__((address_space(1))) void*)src,
          (__attribute__((address_space(3))) void*)(&Bs[buf][g*512]), 16, 0, 0);
    }
  };

  auto compute = [&](int buf) {
    const int par = lane & 7;
    const int gq  = lane >> 4;
    const int r15 = lane & 15;
    #pragma unroll
    for (int ks = 0; ks < 2; ++ks) {
      const int ko = (((ks*4 + gq) ^ par)) * 8;  // swizzled 16B-slot read
      bf16x8 a0 = *(const bf16x8*)&As[buf][(wm*32 + r15)*64 + ko];
      bf16x8 a1 = *(const bf16x8*)&As[buf][(wm*32 + 16 + r15)*64 + ko];
      bf16x8 bfr[5];
      #pragma unroll
      for (int fn = 0; fn < 5; ++fn)
        bfr[fn] = *(const bf16x8*)&Bs[buf][(wn*80 + fn*16 + r15)*64 + ko];
      #pragma unroll
      for (int fn = 0; fn < 5; ++fn) {
        acc[0][fn] = __builtin_amdgcn_mfma_f32_16x16x32_bf16(a0, bfr[fn], acc[0][fn], 0,0,0);
        acc[1][fn] = __builtin_amdgcn_mfma_f32_16x16x32_bf16(a1, bfr[fn], acc[1][fn], 0,0,0);
      }
    }
  };

  stage(0, 0);
  __syncthreads();
  for (int kc = 0; kc < NKC; ++kc) {
    if (kc + 1 < NKC) stage((kc+1)&1, kc+1);
    compute(kc&1);
    __syncthreads();
  }

  // epilogue
  const int oc = (lane>>4)*4, pc = lane&15;
  #pragma unroll
  for (int fm = 0; fm < 2; ++fm) {
    const int o = m0 + wm*32 + fm*16 + oc;
    #pragma unroll
    for (int fn = 0; fn < 5; ++fn) {
      const int p = p0 + wn*80 + fn*16 + pc;
      f32x4 v = acc[fm][fn];
      float4 bv;
      if constexpr (EPI == 0) bv = *(const float4*)&bias[(p % VV)*384 + o];
      else                    bv = *(const float4*)&bias[o];
      float r0 = v[0]+bv.x, r1 = v[1]+bv.y, r2 = v[2]+bv.z, r3 = v[3]+bv.w;
      if constexpr (EPI == 0) {
        int row = (p/VV)*32 + (p%VV);
        ushort4 st; st.x=f2bf(r0); st.y=f2bf(r1); st.z=f2bf(r2); st.w=f2bf(r3);
        *(ushort4*)((u16*)outv + ((size_t)n*1024 + row)*384 + o) = st;
      } else {
        ushort4 st;
        st.x=f2bf(lrelu(r0)); st.y=f2bf(lrelu(r1)); st.z=f2bf(lrelu(r2)); st.w=f2bf(lrelu(r3));
        *(ushort4*)((u16*)outv + ((size_t)n*PIX + p)*256 + o) = st;
      }
    }
  }
}

// ---------------- gemm2_k: fused ff+d2 -> d_out ----------------
// out[o,p] = lrelu( (wd2@xb)[o,p] + bd2[o] + lrelu( (wff@y3b)[o,p] + bff[o] ) )
// Virtual K=512: kc 0..3 -> (wd2, xb) into accD; kc 4..7 -> (wff, y3b) into accF.
// Same LDS/swizzle/staging structure as gemm_k.
__global__ __launch_bounds__(512, 1)
void gemm2_k(const u16* __restrict__ WD2, const u16* __restrict__ WFF,
             const float* __restrict__ bd2, const float* __restrict__ bff,
             const u16* __restrict__ XB, const u16* __restrict__ Y3B,
             float* __restrict__ outp)
{
  __shared__ u16 As[2][128*64];
  __shared__ u16 Bs[2][160*64];
  const int tid = threadIdx.x;
  const int lane = tid & 63, wid = tid >> 6;
  const int wm = wid >> 1, wn = wid & 1;
  const int pt = blockIdx.x, mt = blockIdx.y, n = blockIdx.z;
  const int m0 = mt*128, p0 = pt*160;
  const int lr = lane >> 3;
  const int lc = (((lane & 7) ^ lr)) * 8;

  f32x4 accD[2][5], accF[2][5];
  #pragma unroll
  for (int i = 0; i < 2; ++i)
    #pragma unroll
    for (int j = 0; j < 5; ++j) { accD[i][j] = f32x4{0.f,0.f,0.f,0.f}; accF[i][j] = f32x4{0.f,0.f,0.f,0.f}; }

  auto stage = [&](int buf, int kc) {
    const int kk = kc & 3;
    const u16* Wb = (kc < 4) ? WD2 : WFF;
    const u16* Bb = (kc < 4) ? XB  : Y3B;
    const u16* wsrc = Wb + (size_t)m0*256 + (size_t)kk*64;
    for (int g = wid; g < 16; g += 8) {
      const u16* src = wsrc + (size_t)(g*8 + lr)*256 + lc;
      __builtin_amdgcn_global_load_lds(
          (const __attribute__((address_space(1))) void*)src,
          (__attribute__((address_space(3))) void*)(&As[buf][g*512]), 16, 0, 0);
    }
    const u16* bbase = Bb + ((size_t)n*PIX + p0)*256 + (size_t)kk*64;
    for (int g = wid; g < 20; g += 8) {
      const u16* src = bbase + (size_t)(g*8 + lr)*256 + lc;
      __builtin_amdgcn_global_load_lds(
          (const __attribute__((address_space(1))) void*)src,
          (__attribute__((address_space(3))) void*)(&Bs[buf][g*512]), 16, 0, 0);
    }
  };

  auto compute = [&](int buf, f32x4 (&acc)[2][5]) {
    const int par = lane & 7;
    const int gq  = lane >> 4;
    const int r15 = lane & 15;
    #pragma unroll
    for (int ks = 0; ks < 2; ++ks) {
      const int ko = (((ks*4 + gq) ^ par)) * 8;
      bf16x8 a0 = *(const bf16x8*)&As[buf][(wm*32 + r15)*64 + ko];
      bf16x8 a1 = *(const bf16x8*)&As[buf][(wm*32 + 16 + r15)*64 + ko];
      bf16x8 bfr[5];
      #pragma unroll
      for (int fn = 0; fn < 5; ++fn)
        bfr[fn] = *(const bf16x8*)&Bs[buf][(wn*80 + fn*16 + r15)*64 + ko];
      #pragma unroll
      for (int fn = 0; fn < 5; ++fn) {
        acc[0][fn] = __builtin_amdgcn_mfma_f32_16x16x32_bf16(a0, bfr[fn], acc[0][fn], 0,0,0);
        acc[1][fn] = __builtin_amdgcn_mfma_f32_16x16x32_bf16(a1, bfr[fn], acc[1][fn], 0,0,0);
      }
    }
  };

  stage(0, 0);
  __syncthreads();
  for (int kc = 0; kc < 8; ++kc) {
    if (kc + 1 < 8) stage((kc+1)&1, kc+1);
    if (kc < 4) compute(kc&1, accD); else compute(kc&1, accF);
    __syncthreads();
  }

  // fused epilogue: out = lrelu(accD + bd2 + lrelu(accF + bff)), f32 chan-major
  const int oc = (lane>>4)*4, pc = lane&15;
  #pragma unroll
  for (int fm = 0; fm < 2; ++fm) {
    const int o = m0 + wm*32 + fm*16 + oc;
    const float4 bD = *(const float4*)&bd2[o];
    const float4 bF = *(const float4*)&bff[o];
    #pragma unroll
    for (int fn = 0; fn < 5; ++fn) {
      const int p = p0 + wn*80 + fn*16 + pc;
      f32x4 vD = accD[fm][fn], vF = accF[fm][fn];
      float y40 = lrelu(vF[0]+bF.x), y41 = lrelu(vF[1]+bF.y);
      float y42 = lrelu(vF[2]+bF.z), y43 = lrelu(vF[3]+bF.w);
      float* op = outp + ((size_t)n*256 + o)*PIX + p;
      op[0]      = lrelu(vD[0] + bD.x + y40);
      op[PIX]    = lrelu(vD[1] + bD.y + y41);
      op[2*PIX]  = lrelu(vD[2] + bD.z + y42);
      op[3*PIX]  = lrelu(vD[3] + bD.w + y43);
    }
  }
}

extern "C" void kernel_launch(void* const* d_in, const int* in_sizes, int n_in,
                              void* d_out, int out_size, void* d_ws, size_t ws_size,
                              hipStream_t stream)
{
  const float* x      = (const float*)d_in[0];
  const float* in_w   = (const float*)d_in[1];
  const float* in_b   = (const float*)d_in[2];
  const float* alphas = (const float*)d_in[3];
  const float* att0   = (const float*)d_in[4];
  const float* out_w  = (const float*)d_in[5];
  const float* out_b  = (const float*)d_in[6];
  const float* d1_w   = (const float*)d_in[7];
  const float* d1_b   = (const float*)d_in[8];
  const float* d2_w   = (const float*)d_in[9];
  const float* d2_b   = (const float*)d_in[10];
  const float* ff_w   = (const float*)d_in[11];
  const float* ff_b   = (const float*)d_in[12];
  const float* out_g  = (const float*)d_in[13];
  const float* out_be = (const float*)d_in[14];
  const float* out_m  = (const float*)d_in[15];
  const float* out_v  = (const float*)d_in[16];
  const float* d1_g   = (const float*)d_in[17];
  const float* d1_be  = (const float*)d_in[18];
  const float* d1_m   = (const float*)d_in[19];
  const float* d1_v   = (const float*)d_in[20];
  const float* d2_g   = (const float*)d_in[21];
  const float* d2_be  = (const float*)d_in[22];
  const float* d2_m   = (const float*)d_in[23];
  const float* d2_v   = (const float*)d_in[24];
  const float* ff_g   = (const float*)d_in[25];
  const float* ff_be  = (const float*)d_in[26];
  const float* ff_m   = (const float*)d_in[27];
  const float* ff_v   = (const float*)d_in[28];

  char* ws = (char*)d_ws;
  float* pe  = (float*)(ws + OFF_PE);
  u16*  w1b  = (u16*)(ws + OFF_W1);
  u16*  wk2  = (u16*)(ws + OFF_WK2);
  u16*  wff  = (u16*)(ws + OFF_WFF);
  u16*  wd2  = (u16*)(ws + OFF_WD2);
  float* b1v = (float*)(ws + OFF_B1);
  float* bk2 = (float*)(ws + OFF_BK2);
  float* bff = (float*)(ws + OFF_BFF);
  float* bd2 = (float*)(ws + OFF_BD2);
  u16*  attb = (u16*)(ws + OFF_ATT);
  u16*  xb   = (u16*)(ws + OFF_XB);
  u16*  qkb  = (u16*)(ws + OFF_BIG);   // [128][1024][384]
  u16*  Pb   = (u16*)(ws + OFF_BIG);   // [128][800][768]  (after att done)
  u16*  y3b  = (u16*)(ws + OFF_Y3);    // [128][800][256]

  prep_k<<<256, 256, 0, stream>>>(
      in_w, in_b, out_w, out_b, d1_w, d1_b, d2_w, d2_b, ff_w, ff_b,
      out_g, out_be, out_m, out_v, d1_g, d1_be, d1_m, d1_v,
      d2_g, d2_be, d2_m, d2_v, ff_g, ff_be, ff_m, ff_v,
      pe, w1b, wk2, bk2, wff, bff, wd2, bd2, qkb);

  prep2_k<<<(384*VV + 255)/256, 256, 0, stream>>>(in_w, in_b, pe, b1v);

  k0_cvt<<<dim3(TT, NB), 256, 0, stream>>>(x, xb);

  // qk = in_w @ x + b1v(o,v)   -> qkb (padded pixel-major)
  gemm_k<256, 4, 256, 256, 0><<<dim3(5, 3, NB), 512, 0, stream>>>(w1b, b1v, xb, xb, qkb);

  att_k<<<dim3(SSS, NB), 256, 0, stream>>>(qkb, alphas, att0, attb);

  p_k2<<<dim3(TT, NB), 256, 0, stream>>>(xb, attb, Pb);

  // y3 = lrelu( bn(out_w @ P) + bn(d1_w @ x) )   (K=1024 fused)
  gemm_k<1024, 12, 768, 256, 1><<<dim3(5, 2, NB), 512, 0, stream>>>(wk2, bk2, Pb, xb, y3b);

  // out = lrelu( bn(d2_w @ x) + lrelu(bn(ff_w @ y3)) )   (fused ff+d2)
  gemm2_k<<<dim3(5, 2, NB), 512, 0, stream>>>(wd2, wff, bd2, bff, xb, y3b, (float*)d_out);
}